// Round 11
// baseline (1573.793 us; speedup 1.0000x reference)
//
#include <hip/hip_runtime.h>
#include <math.h>

#define NPTS 2048
#define BATCH 8
#define KNB 10
#define NT (NPTS*KNB)   // 20480 positions per batch (point*10+j)

static __device__ __forceinline__ float lrelu(float x, float s){ return x >= 0.f ? x : s*x; }
static __device__ __forceinline__ double lrelu_d(double x, double s){ return x >= 0.0 ? x : s*x; }

// ---------------------------------------------------------------------------
// Tiled GEMM with fused epilogue. EXACT=true bit-matches numpy einsum
// 'bcn,oc->bon' (+bias, opt lrelu): single f32 acc, ascending k, no FMA.
// ---------------------------------------------------------------------------
template<int TM, int TN, bool EXACT=false>
__global__ __launch_bounds__(256) void gemm_bn(
    const float* __restrict__ In, int ldn, size_t inBS, int koff,
    const float* __restrict__ W, int wstride, int wcol0,
    const float* __restrict__ cb, const float* __restrict__ bng, const float* __restrict__ bnb,
    const float* __restrict__ addBO, int addM,
    float* __restrict__ Out, int ldo, size_t outBS,
    int C, int act, float neg, int bbase)
{
  constexpr int RM = TM/16, RN = TN/16;
  __shared__ float As[16][TM+4];
  __shared__ float Bs[16][TN+4];
  const int b = bbase + blockIdx.z;
  const float* in = In + (size_t)b*inBS;
  float* outp = Out + (size_t)b*outBS;
  const int m0 = blockIdx.y*TM, n0 = blockIdx.x*TN;
  const int t = threadIdx.x;
  const int tmv = t>>4, tnv = t&15;
  float acc[RM][RN] = {};
  for (int k0=0; k0<C; k0+=16){
    #pragma unroll
    for (int s=0;s<RM;s++){
      const int i = t + s*256;
      const int k = i&15, m = i>>4;
      As[k][m] = W[(size_t)(m0+m)*wstride + wcol0 + k0 + k];
    }
    #pragma unroll
    for (int s=0;s<RN;s++){
      const int i = t + s*256;
      const int n = i & (TN-1), kk2 = i / TN;
      Bs[kk2][n] = in[(size_t)(koff + k0 + kk2)*ldn + n0 + n];
    }
    __syncthreads();
    #pragma unroll
    for (int kk=0;kk<16;kk++){
      float av[RM], bv[RN];
      #pragma unroll
      for (int s=0;s<RM/4;s++){
        float4 v = *(const float4*)&As[kk][tmv*RM + s*4];
        av[s*4]=v.x; av[s*4+1]=v.y; av[s*4+2]=v.z; av[s*4+3]=v.w;
      }
      #pragma unroll
      for (int s=0;s<RN/4;s++){
        float4 v = *(const float4*)&Bs[kk][tnv*RN + s*4];
        bv[s*4]=v.x; bv[s*4+1]=v.y; bv[s*4+2]=v.z; bv[s*4+3]=v.w;
      }
      #pragma unroll
      for (int i2=0;i2<RM;i2++)
        #pragma unroll
        for (int j2=0;j2<RN;j2++){
          if constexpr (EXACT)
            acc[i2][j2] = __fadd_rn(acc[i2][j2], __fmul_rn(av[i2], bv[j2]));
          else
            acc[i2][j2] += av[i2]*bv[j2];
        }
    }
    __syncthreads();
  }
  const float rs = 1.f/sqrtf(1.f + 1e-5f);
  #pragma unroll
  for (int i2=0;i2<RM;i2++){
    const int gm = m0 + tmv*RM + i2;
    float addv = cb ? cb[gm] : 0.f;
    if (addBO) addv += addBO[b*addM + gm];
    float sc = 1.f, bs = 0.f;
    if (bng){ sc = bng[gm]*rs; bs = bnb[gm]; }
    float* orow = outp + (size_t)gm*ldo + n0 + tnv*RN;
    #pragma unroll
    for (int j4=0;j4<RN/4;j4++){
      float4 o;
      float vv[4];
      #pragma unroll
      for (int q=0;q<4;q++){
        float v;
        if constexpr (EXACT){
          v = __fadd_rn(acc[i2][j4*4+q], addv);
          if (act) v = (v >= 0.f) ? v : __fmul_rn(neg, v);
        } else {
          v = acc[i2][j4*4+q] + addv;
          if (bng) v = v*sc + bs;
          if (act) v = lrelu(v, neg);
        }
        vv[q] = v;
      }
      o.x=vv[0]; o.y=vv[1]; o.z=vv[2]; o.w=vv[3];
      *(float4*)&orow[j4*4] = o;
    }
  }
}

// ---------------------------------------------------------------------------
// Head layer 1 (EXACT): C=131 gathered from x (B,N,3), z (B,N,128); lrelu 0.01
// ---------------------------------------------------------------------------
__global__ __launch_bounds__(256) void head1_exact(
    const float* __restrict__ x, const float* __restrict__ z,
    const float* __restrict__ W, const float* __restrict__ bias,
    float* __restrict__ outh)
{
  __shared__ float As[16][68];
  __shared__ float Bs[16][68];
  const int b = blockIdx.z;
  const int m0 = blockIdx.y*64, n0 = blockIdx.x*64;
  const int t = threadIdx.x;
  const int tm = t>>4, tn = t&15;
  float acc[4][4] = {};
  for (int k0 = 0; k0 < 144; k0 += 16){
    #pragma unroll
    for (int i=0;i<4;i++){
      const int ii = t + i*256;
      const int k = ii&15, m = ii>>4;
      const int gk = k0+k;
      As[k][m] = (gk<131) ? W[(size_t)(m0+m)*131 + gk] : 0.f;
    }
    #pragma unroll
    for (int i=0;i<4;i++){
      const int ii = t + i*256;
      const int k = ii&15, nn = ii>>4;
      const int gk = k0+k, gn = n0+nn;
      float v = 0.f;
      if (gk < 3)        v = x[((size_t)b*NPTS+gn)*3   + gk];
      else if (gk < 131) v = z[((size_t)b*NPTS+gn)*128 + (gk-3)];
      Bs[k][nn] = v;
    }
    __syncthreads();
    #pragma unroll
    for (int k=0;k<16;k++){
      #pragma unroll
      for (int i=0;i<4;i++){
        const float a = As[k][tm*4+i];
        #pragma unroll
        for (int j=0;j<4;j++){
          acc[i][j] = __fadd_rn(acc[i][j], __fmul_rn(a, Bs[k][tn*4+j]));
        }
      }
    }
    __syncthreads();
  }
  #pragma unroll
  for (int i=0;i<4;i++){
    const int gm = m0 + tm*4 + i;
    #pragma unroll
    for (int j=0;j<4;j++){
      float v = __fadd_rn(acc[i][j], bias[gm]);
      v = (v >= 0.f) ? v : __fmul_rn(0.01f, v);
      outh[((size_t)b*128+gm)*NPTS + n0 + tn*4 + j] = v;
    }
  }
}

// ---------------------------------------------------------------------------
// Block-1 kNN: f32 np-exact.
// ---------------------------------------------------------------------------
__global__ __launch_bounds__(256) void norms3_f32(const float* __restrict__ Xn, float* __restrict__ XN)
{
  const int q = blockIdx.x*256 + threadIdx.x;
  const float* p = Xn + (size_t)q*3;
  float s = __fmul_rn(p[0],p[0]);
  s = __fadd_rn(s, __fmul_rn(p[1],p[1]));
  s = __fadd_rn(s, __fmul_rn(p[2],p[2]));
  XN[q] = s;
}

__global__ __launch_bounds__(256) void knn_part3(
    const float* __restrict__ Xn, const float* __restrict__ XN,
    double* __restrict__ topd, int* __restrict__ topi)
{
  const int t = threadIdx.x;
  const int qloc = t & 31, part = t >> 5;
  const int q = blockIdx.x*32 + qloc;
  const int b = q >> 11, n = q & (NPTS-1);
  const float* xb = Xn + (size_t)b*NPTS*3;
  const float qx = xb[(size_t)n*3+0], qy = xb[(size_t)n*3+1], qz = xb[(size_t)n*3+2];
  const float qn = XN[q];
  float td[11]; int ti[11];
  #pragma unroll
  for (int r=0;r<11;r++){ td[r] = 3.4e38f; ti[r] = 0x7fffffff; }
  const int m0 = part*(NPTS/8);
  for (int mm=0; mm<NPTS/8; mm++){
    const int m = m0 + mm;
    float dot = __fmul_rn(qx, xb[(size_t)m*3+0]);
    dot = __fadd_rn(dot, __fmul_rn(qy, xb[(size_t)m*3+1]));
    dot = __fadd_rn(dot, __fmul_rn(qz, xb[(size_t)m*3+2]));
    float dist = __fmul_rn(-2.f, dot);
    dist = __fadd_rn(dist, qn);
    dist = __fadd_rn(dist, XN[b*NPTS + m]);
    if (dist < td[10]){
      td[10] = dist; ti[10] = m;
      #pragma unroll
      for (int p=10;p>0;p--){
        if (td[p] < td[p-1]){
          float tf=td[p]; td[p]=td[p-1]; td[p-1]=tf;
          int   tt=ti[p]; ti[p]=ti[p-1]; ti[p-1]=tt;
        }
      }
    }
  }
  const size_t base = ((size_t)q*8 + part)*11;
  #pragma unroll
  for (int r=0;r<11;r++){ topd[base+r] = (double)td[r]; topi[base+r] = ti[r]; }
}

__global__ __launch_bounds__(256) void knn_merge_kernel(
    const double* __restrict__ topd, const int* __restrict__ topi, int* __restrict__ idxout)
{
  const int q = blockIdx.x*256 + threadIdx.x;
  double td[11]; int ti[11];
  #pragma unroll
  for (int r=0;r<11;r++){ td[r] = 1.0e308; ti[r] = 0x7fffffff; }
  const size_t base = (size_t)q*88;
  for (int s=0; s<88; s++){
    const double d = topd[base+s];
    const int  im = topi[base+s];
    if (d < td[10] || (d == td[10] && im < ti[10])){
      td[10] = d; ti[10] = im;
      #pragma unroll
      for (int p=10;p>0;p--){
        const bool sw = (td[p] < td[p-1]) || (td[p] == td[p-1] && ti[p] < ti[p-1]);
        if (sw){
          double tf=td[p]; td[p]=td[p-1]; td[p-1]=tf;
          int    tt=ti[p]; ti[p]=ti[p-1]; ti[p-1]=tt;
        }
      }
    }
  }
  #pragma unroll
  for (int j=0;j<KNB;j++) idxout[(size_t)q*KNB + j] = ti[j+1];
}

// ---------------------------------------------------------------------------
// Block-2 kNN stage 1: LDS-tiled candidates (double-buffered) + in-register
// top-16. Block = 32 queries; thread (q,p): list p owns candidates m%8==p,
// ascending (stable). Tile t+1 loads overlap tile t compute; 1 barrier/tile.
// Same insert order as R8/R9 -> bit-identical lists -> identical IDX.
// ---------------------------------------------------------------------------
__global__ __launch_bounds__(256) void norms64_f32(const float* __restrict__ Xn, float* __restrict__ XN)
{
  const int q = blockIdx.x*256 + threadIdx.x;
  const float4* p4 = (const float4*)(Xn + (size_t)q*64);
  float s0=0.f,s1=0.f,s2=0.f,s3=0.f;
  #pragma unroll
  for (int d4=0; d4<16; d4++){
    float4 v = p4[d4];
    s0 += v.x*v.x; s1 += v.y*v.y; s2 += v.z*v.z; s3 += v.w*v.w;
  }
  XN[q] = (s0+s1)+(s2+s3);
}

__global__ __launch_bounds__(256) void knn_coarse(
    const float* __restrict__ Xn, const float* __restrict__ XN,
    float* __restrict__ topf, int* __restrict__ topi)
{
  __shared__ float Cs[2][64][68];
  __shared__ float xns[2][64];
  const int t = threadIdx.x;
  const int tq = t>>3, p = t&7;
  const int q0 = blockIdx.x*32;
  const int b  = q0 >> 11;
  const int gq = q0 + tq;
  const int nloc = (q0 & (NPTS-1)) + tq;
  const float* xb = Xn + (size_t)b*NPTS*64;
  float qv[64];
  {
    const float4* p4 = (const float4*)(xb + (size_t)nloc*64);
    #pragma unroll
    for (int d4=0; d4<16; d4++){ float4 v = p4[d4]; qv[d4*4]=v.x; qv[d4*4+1]=v.y; qv[d4*4+2]=v.z; qv[d4*4+3]=v.w; }
  }
  const float qn = XN[gq];
  float td[16]; int ti[16];
  #pragma unroll
  for (int r=0;r<16;r++){ td[r] = 3.4e38f; ti[r] = 0x7fffffff; }

  // preload tile 0 into buffer 0
  {
    #pragma unroll
    for (int s=0;s<4;s++){
      const int i = t + s*256;
      const int row = i>>4, f4 = i&15;
      float4 v = *(const float4*)(xb + (size_t)row*64 + f4*4);
      *(float4*)&Cs[0][row][f4*4] = v;
    }
    if (t < 64) xns[0][t] = XN[b*NPTS + t];
  }
  __syncthreads();

  int buf = 0;
  for (int m0=0; m0<NPTS; m0+=64){
    const int nxt = m0 + 64;
    if (nxt < NPTS){
      #pragma unroll
      for (int s=0;s<4;s++){
        const int i = t + s*256;
        const int row = i>>4, f4 = i&15;
        float4 v = *(const float4*)(xb + (size_t)(nxt+row)*64 + f4*4);
        *(float4*)&Cs[buf^1][row][f4*4] = v;
      }
      if (t < 64) xns[buf^1][t] = XN[b*NPTS + nxt + t];
    }
    #pragma unroll
    for (int jj=0;jj<8;jj++){
      const int row = jj*8 + p;
      float d0=0.f,d1=0.f,d2=0.f,d3=0.f;
      #pragma unroll
      for (int k4=0;k4<16;k4++){
        float4 v = *(const float4*)&Cs[buf][row][k4*4];
        d0 += qv[k4*4+0]*v.x; d1 += qv[k4*4+1]*v.y;
        d2 += qv[k4*4+2]*v.z; d3 += qv[k4*4+3]*v.w;
      }
      const float dist = qn - 2.f*((d0+d1)+(d2+d3)) + xns[buf][row];
      const int m = m0 + row;
      if (dist < td[15]){
        td[15] = dist; ti[15] = m;
        #pragma unroll
        for (int pp=15;pp>0;pp--){
          if (td[pp] < td[pp-1]){
            float tf=td[pp]; td[pp]=td[pp-1]; td[pp-1]=tf;
            int   tt=ti[pp]; ti[pp]=ti[pp-1]; ti[pp-1]=tt;
          }
        }
      }
    }
    __syncthreads();
    buf ^= 1;
  }
  const size_t base = ((size_t)gq*8 + p)*16;
  #pragma unroll
  for (int r=0;r<16;r++){ topf[base+r] = td[r]; topi[base+r] = ti[r]; }
}

// ---------------------------------------------------------------------------
// Block-2 kNN stage 2: merge 8x16 -> global f32 top-16, f64 re-rank, emit 10.
// ---------------------------------------------------------------------------
__global__ __launch_bounds__(256) void norms64d(const double* __restrict__ Xn, double* __restrict__ XN)
{
  const int q = blockIdx.x*256 + threadIdx.x;
  const double* p = Xn + (size_t)q*64;
  double s = 0.0;
  #pragma unroll
  for (int d=0; d<64; d++) s += p[d]*p[d];
  XN[q] = s;
}

__global__ __launch_bounds__(256) void knn_refine(
    const float* __restrict__ topf, const int* __restrict__ topi,
    const double* __restrict__ Xd, const double* __restrict__ XNd,
    int* __restrict__ idxout)
{
  const int q = blockIdx.x*256 + threadIdx.x;
  const int b = q >> 11;
  float tf[16]; int ti[16];
  #pragma unroll
  for (int r=0;r<16;r++){ tf[r] = 3.4e38f; ti[r] = 0x7fffffff; }
  const size_t base = (size_t)q*128;
  for (int s=0; s<128; s++){
    const float d = topf[base+s];
    const int  im = topi[base+s];
    if (d < tf[15] || (d == tf[15] && im < ti[15])){
      tf[15] = d; ti[15] = im;
      #pragma unroll
      for (int p=15;p>0;p--){
        const bool sw = (tf[p] < tf[p-1]) || (tf[p] == tf[p-1] && ti[p] < ti[p-1]);
        if (sw){
          float a=tf[p]; tf[p]=tf[p-1]; tf[p-1]=a;
          int   c=ti[p]; ti[p]=ti[p-1]; ti[p-1]=c;
        }
      }
    }
  }
  double qv[64];
  {
    const double2* p2 = (const double2*)(Xd + (size_t)q*64);
    #pragma unroll
    for (int d2=0; d2<32; d2++){ double2 v = p2[d2]; qv[d2*2]=v.x; qv[d2*2+1]=v.y; }
  }
  const double qn = XNd[q];
  double dd[11]; int di[11];
  #pragma unroll
  for (int r=0;r<11;r++){ dd[r] = 1.0e308; di[r] = 0x7fffffff; }
  for (int s=0; s<16; s++){
    const int m = ti[s];
    const double2* c2 = (const double2*)(Xd + ((size_t)(b*NPTS + m))*64);
    double d0=0.0,d1=0.0,d2s=0.0,d3=0.0;
    #pragma unroll
    for (int d4=0; d4<16; d4++){
      double2 va = c2[d4*2], vb = c2[d4*2+1];
      d0 += qv[d4*4+0]*va.x; d1 += qv[d4*4+1]*va.y;
      d2s+= qv[d4*4+2]*vb.x; d3 += qv[d4*4+3]*vb.y;
    }
    const double dot = (d0+d1)+(d2s+d3);
    const double dist = (qn - 2.0*dot) + XNd[b*NPTS + m];
    if (dist < dd[10] || (dist == dd[10] && m < di[10])){
      dd[10] = dist; di[10] = m;
      #pragma unroll
      for (int p=10;p>0;p--){
        const bool sw = (dd[p] < dd[p-1]) || (dd[p] == dd[p-1] && di[p] < di[p-1]);
        if (sw){
          double a=dd[p]; dd[p]=dd[p-1]; dd[p-1]=a;
          int    c=di[p]; di[p]=di[p-1]; di[p-1]=c;
        }
      }
    }
  }
  #pragma unroll
  for (int j=0;j<KNB;j++) idxout[(size_t)q*KNB + j] = di[j+1];
}

// ---------------------------------------------------------------------------
// Edge block 1 (mixed precision, np-matched) — register-ized (R9, proven).
// ---------------------------------------------------------------------------
__global__ __launch_bounds__(512) void edge1_f64(
    const float* __restrict__ Xn, const int* __restrict__ idx,
    const float* __restrict__ wc1, const float* __restrict__ wcb1,
    const float* __restrict__ bn1g, const float* __restrict__ bn1b,
    const float* __restrict__ wc2, const float* __restrict__ wcb2,
    const float* __restrict__ bn2g, const float* __restrict__ bn2b,
    const float* __restrict__ xc,  const float* __restrict__ xcb,
    const float* __restrict__ xbng, const float* __restrict__ xbnb,
    const float* __restrict__ oWT, const float* __restrict__ ob,
    double* __restrict__ outX)
{
  __shared__ double w1bd[8][32];
  __shared__ float smw2[4096];
  __shared__ double hwbd[8][64];

  const int t = threadIdx.x;
  const int wid = t>>6, lane = t&63;
  const double sq = sqrt(1.0 + 1e-5);
  const int m31 = lane & 31;

  float wc1row[3];
  wc1row[0] = wc1[m31*3+0]; wc1row[1] = wc1[m31*3+1]; wc1row[2] = wc1[m31*3+2];
  const float wcb1r = wcb1[m31];
  const double fs1r = (double)bn1g[m31]/sq, fb1r = (double)bn1b[m31];
  float wc2row[32];
  #pragma unroll
  for (int m=0;m<32;m++) wc2row[m] = wc2[lane*32 + m];
  const float wcb2r = wcb2[lane];
  const double fs2r = (double)bn2g[lane]/sq, fb2r = (double)bn2b[lane];
  float xcrow[6];
  #pragma unroll
  for (int c=0;c<6;c++) xcrow[c] = xc[lane*6 + c];
  const float xcbr = xcb[lane];
  const double fsxr = (double)xbng[lane]/sq, fbxr = (double)xbnb[lane];

  const int p = blockIdx.x*8 + wid;
  const int b = p >> 11, n = p & (NPTS-1);
  const float* xb = Xn + (size_t)b*NPTS*3;
  const float cen0 = xb[(size_t)n*3+0];
  const float cen1 = xb[(size_t)n*3+1];
  const float cen2 = xb[(size_t)n*3+2];
  const int* ip = idx + ((size_t)b*NPTS + n)*KNB;

  double w2r[KNB], hr[KNB];
  #pragma unroll
  for (int j=0;j<KNB;j++){
    const int id = ip[j];
    const float dif0 = __fadd_rn(xb[(size_t)id*3+0], -cen0);
    const float dif1 = __fadd_rn(xb[(size_t)id*3+1], -cen1);
    const float dif2 = __fadd_rn(xb[(size_t)id*3+2], -cen2);
    {
      float s = __fmul_rn(wc1row[0], dif0);
      s = __fadd_rn(s, __fmul_rn(wc1row[1], dif1));
      s = __fadd_rn(s, __fmul_rn(wc1row[2], dif2));
      s = __fadd_rn(s, wcb1r);
      const double w1v = lrelu_d((double)s * fs1r + fb1r, 0.01);
      if (lane < 32) w1bd[wid][lane] = w1v;
    }
    __builtin_amdgcn_wave_barrier();
    {
      double s2 = 0.0;
      #pragma unroll 8
      for (int m=0;m<32;m++) s2 += (double)wc2row[m] * w1bd[wid][m];
      s2 += (double)wcb2r;
      w2r[j] = lrelu_d(s2*fs2r + fb2r, 0.01);
    }
    {
      float s3 = __fmul_rn(xcrow[0], cen0);
      s3 = __fadd_rn(s3, __fmul_rn(xcrow[1], cen1));
      s3 = __fadd_rn(s3, __fmul_rn(xcrow[2], cen2));
      s3 = __fadd_rn(s3, __fmul_rn(xcrow[3], dif0));
      s3 = __fadd_rn(s3, __fmul_rn(xcrow[4], dif1));
      s3 = __fadd_rn(s3, __fmul_rn(xcrow[5], dif2));
      s3 = __fadd_rn(s3, xcbr);
      hr[j] = lrelu_d((double)s3*fsxr + fbxr, 0.01);
    }
    __builtin_amdgcn_wave_barrier();
  }

  double hw[KNB];
  {
    double mx = w2r[0];
    #pragma unroll
    for (int j=1;j<KNB;j++) mx = fmax(mx, w2r[j]);
    double ssum = 0.0;
    #pragma unroll
    for (int j=0;j<KNB;j++){ const double e = exp(w2r[j]-mx); w2r[j]=e; ssum+=e; }
    #pragma unroll
    for (int j=0;j<KNB;j++) hw[j] = hr[j]*(w2r[j]/ssum);
  }

  double acc = 0.0;
  #pragma unroll
  for (int j=0;j<KNB;j++){
    __syncthreads();
    for (int i=t; i<4096; i+=512) smw2[i] = oWT[(size_t)j*4096 + i];
    hwbd[wid][lane] = hw[j];
    __syncthreads();
    double s = 0.0;
    #pragma unroll 8
    for (int c=0;c<64;c++) s += (double)smw2[c*64 + lane]*hwbd[wid][c];
    acc += s;
  }
  outX[((size_t)b*64+lane)*NPTS + n] = acc + (double)ob[lane];
}

template<int CH>
__global__ void owt_kernel(const float* __restrict__ oW, float* __restrict__ oWT)
{
  const int i = blockIdx.x*256 + threadIdx.x;
  if (i < CH*CH*KNB){
    const int j  = i % KNB;
    const int c2 = (i / KNB) % CH;
    const int o  = i / (KNB*CH);
    oWT[((size_t)j*CH + c2)*CH + o] = oW[i];
  }
}

__global__ __launch_bounds__(256) void adain1_f64(
    double* __restrict__ X, const float* __restrict__ S)
{
  const int c = blockIdx.x, b = blockIdx.y;
  const int t = threadIdx.x;
  const size_t base = ((size_t)b*64 + c)*NPTS;
  __shared__ double red[256];
  double v[8];
  double s = 0.0;
  #pragma unroll
  for (int i=0;i<8;i++){
    double xv = X[base + t + i*256];
    xv = lrelu_d(xv, 0.2);
    v[i] = xv; s += xv;
  }
  red[t] = s; __syncthreads();
  for (int st=128; st>0; st>>=1){ if (t<st) red[t] += red[t+st]; __syncthreads(); }
  const double mean = red[0]/(double)NPTS;
  __syncthreads();
  double s2 = 0.0;
  #pragma unroll
  for (int i=0;i<8;i++){ const double d = v[i]-mean; s2 += d*d; }
  red[t] = s2; __syncthreads();
  for (int st=128; st>0; st>>=1){ if (t<st) red[t] += red[t+st]; __syncthreads(); }
  const double var  = red[0]/(double)NPTS;
  const double rstd = 1.0/sqrt(var + 1e-5);
  const float* g  = S + ((size_t)b*128 + c)*NPTS;
  const float* be = S + ((size_t)b*128 + 64 + c)*NPTS;
  #pragma unroll
  for (int i=0;i<8;i++){
    const int n = t + i*256;
    X[base+n] = (double)g[n]*((v[i]-mean)*rstd) + (double)be[n];
  }
}

// (B,64,N) f64 chan-major -> X1T64 (B,N,64) f64, X1f (B,N,64) f32, X1c (B,64,N) f32
__global__ __launch_bounds__(256) void transpose_cast64(
    const double* __restrict__ in, double* __restrict__ outT,
    float* __restrict__ outTf, float* __restrict__ outC)
{
  __shared__ double tile[64][65];
  const int b = blockIdx.y, n0 = blockIdx.x*64;
  const int t = threadIdx.x;
  for (int i=t; i<4096; i+=256){
    const int n=i&63, c=i>>6;
    const double v = in[((size_t)b*64+c)*NPTS + n0+n];
    tile[c][n] = v;
    outC[((size_t)b*64+c)*NPTS + n0+n] = (float)v;
  }
  __syncthreads();
  for (int i=t; i<4096; i+=256){
    const int c=i&63, n=i>>6;
    const double v = tile[c][n];
    outT [((size_t)b*NPTS+n0+n)*64 + c] = v;
    outTf[((size_t)b*NPTS+n0+n)*64 + c] = (float)v;
  }
}

// ---------------------------------------------------------------------------
// Kernel P: per-point center GEMMs (WCC, HCC).
// ---------------------------------------------------------------------------
__global__ __launch_bounds__(256) void kernelP(
    const float* __restrict__ x1c, const float* __restrict__ wc1,
    const float* __restrict__ xc,
    float* __restrict__ WCC, float* __restrict__ HCC)
{
  __shared__ float As[16][68];
  __shared__ float Bs[16][132];
  const int b = blockIdx.z;
  const int y = blockIdx.y;
  const int n0 = blockIdx.x*128;
  const int t = threadIdx.x;
  const int tm = t>>4, tn = t&15;
  float acc[4][8] = {};
  for (int k0=0; k0<64; k0+=16){
    #pragma unroll
    for (int s=0;s<4;s++){
      const int i = t + s*256;
      const int k = i&15, m = i>>4;
      float w;
      if (y == 0) w = wc1[(size_t)m*64 + k0 + k];
      else {
        const int c = (y-1)*64 + m;
        w = xc[(size_t)c*128 + k0 + k] - xc[(size_t)c*128 + 64 + k0 + k];
      }
      As[k][m] = w;
    }
    #pragma unroll
    for (int s=0;s<8;s++){
      const int i = t + s*256;
      const int n = i&127, kk = i>>7;
      Bs[kk][n] = x1c[((size_t)b*64 + k0 + kk)*NPTS + n0 + n];
    }
    __syncthreads();
    #pragma unroll
    for (int k=0;k<16;k++){
      float4 a4 = *(const float4*)&As[k][tm*4];
      const float av[4] = {a4.x, a4.y, a4.z, a4.w};
      #pragma unroll
      for (int j=0;j<8;j++){
        const float bv = Bs[k][tn + j*16];
        #pragma unroll
        for (int i2=0;i2<4;i2++) acc[i2][j] += av[i2]*bv;
      }
    }
    __syncthreads();
  }
  #pragma unroll
  for (int i2=0;i2<4;i2++){
    const int m = tm*4 + i2;
    #pragma unroll
    for (int j=0;j<8;j++){
      const int n = n0 + tn + j*16;
      if (y == 0) WCC[((size_t)b*64 + m)*NPTS + n] = acc[i2][j];
      else        HCC[((size_t)b*128 + (y-1)*64 + m)*NPTS + n] = acc[i2][j];
    }
  }
}

// ---------------------------------------------------------------------------
// Kernel A: w1 = lrelu(bn1( wc1@nbr - WCC + wcb1 ))
// ---------------------------------------------------------------------------
__global__ __launch_bounds__(256) void kernelA(
    const float* __restrict__ X1f, const int* __restrict__ IDX,
    const float* __restrict__ WCC,
    const float* __restrict__ wc1, const float* __restrict__ wcb1,
    const float* __restrict__ bn1g, const float* __restrict__ bn1b,
    float* __restrict__ W1, int bbase)
{
  __shared__ float wc1T[64*68];
  __shared__ float nbr[64*132];
  __shared__ int idx_l[128];
  const int b = bbase + blockIdx.z;
  const int n0 = blockIdx.x*128;
  const int t = threadIdx.x;
  const float* xb = X1f + (size_t)b*NPTS*64;

  if (t < 128){
    const int n = n0 + t;
    idx_l[t] = IDX[((size_t)b*NPTS + n/10)*KNB + (n%10)];
  }
  for (int i=t; i<4096; i+=256){
    const int k = i&63, m = i>>6;
    wc1T[k*68 + m] = wc1[(size_t)m*64 + k];
  }
  __syncthreads();
  const float4* xb4 = (const float4*)xb;
  #pragma unroll
  for (int r=0; r<8; r++){
    const int i = t + r*256;
    const int pos = i>>4, q4 = i&15;
    const float4 v = xb4[(size_t)idx_l[pos]*16 + q4];
    nbr[(q4*4+0)*132 + pos] = v.x;
    nbr[(q4*4+1)*132 + pos] = v.y;
    nbr[(q4*4+2)*132 + pos] = v.z;
    nbr[(q4*4+3)*132 + pos] = v.w;
  }
  __syncthreads();

  const int tm = t>>4, tn = t&15;
  float acc[4][8] = {};
  #pragma unroll 4
  for (int k=0;k<64;k++){
    float4 a4 = *(const float4*)&wc1T[k*68 + tm*4];
    const float av[4] = {a4.x, a4.y, a4.z, a4.w};
    #pragma unroll
    for (int j=0;j<8;j++){
      const float bv = nbr[k*132 + tn + j*16];
      #pragma unroll
      for (int i2=0;i2<4;i2++) acc[i2][j] += av[i2]*bv;
    }
  }
  const float rs = 1.f/sqrtf(1.f + 1e-5f);
  #pragma unroll
  for (int i2=0;i2<4;i2++){
    const int m = tm*4 + i2;
    const float bias = wcb1[m];
    const float sc = bn1g[m]*rs, bb = bn1b[m];
    #pragma unroll
    for (int j=0;j<8;j++){
      const int n = n0 + tn + j*16;
      const int p = n/10;
      float v = acc[i2][j] - WCC[((size_t)b*64 + m)*NPTS + p] + bias;
      v = lrelu(v*sc + bb, 0.01f);
      W1[((size_t)(b-bbase)*64 + m)*NT + n] = v;
    }
  }
}

// ---------------------------------------------------------------------------
// Kernel C (chunked channels: 2 x 64): fused w2-GEMM + h-GEMM + softmax +
// partial output einsum. LDS union 19200 floats (76.8 KB) -> 2 blocks/CU.
// ---------------------------------------------------------------------------
#define C_WC2T 0
#define C_XCDT 4352
#define C_W1S  8704
#define C_NBRS 13952
#define C_TOT  19200
#define C_HW   0       /* [8][648] = 5184 */
#define C_OWL  5184    /* [128][65] = 8320 -> end 13504 */

__global__ __launch_bounds__(256) void kernelC(
    const float* __restrict__ X1f, const int* __restrict__ IDX,
    const float* __restrict__ W1, const float* __restrict__ HCC,
    const float* __restrict__ wc2, const float* __restrict__ wcb2,
    const float* __restrict__ bn2g, const float* __restrict__ bn2b,
    const float* __restrict__ xc,  const float* __restrict__ xcb,
    const float* __restrict__ xbng, const float* __restrict__ xbnb,
    const float* __restrict__ oW, const float* __restrict__ ob,
    float* __restrict__ X2, int bbase)
{
  __shared__ float smC[C_TOT];
  __shared__ int idxC[80];
  const int b = bbase + blockIdx.z;
  const int n0 = blockIdx.x*80;
  const int p0 = n0/10;
  const int t = threadIdx.x;
  const float* xb = X1f + (size_t)b*NPTS*64;

  if (t < 80){
    const int n = n0 + t;
    idxC[t] = IDX[((size_t)b*NPTS + n/10)*KNB + (n%10)];
  }
  __syncthreads();

  const int tmv = t>>4, tnv = t&15, tnv5 = tnv*5;
  const int p_loc = tnv>>1, jh5 = (tnv&1)*5;
  const int o = t&127, phalf = t>>7;
  const float rs = 1.f/sqrtf(1.f + 1e-5f);
  float acc2[4] = {};

  for (int ch=0; ch<2; ch++){
    for (int i=t; i<4096; i+=256){
      const int k = i&63, cl = i>>6;
      smC[C_WC2T + k*68 + cl] = wc2[(size_t)(ch*64+cl)*64 + k];
      smC[C_XCDT + k*68 + cl] = xc[(size_t)(ch*64+cl)*128 + 64 + k];
    }
    for (int i=t; i<5120; i+=256){
      const int n = i%80, k = i/80;
      smC[C_W1S + k*82 + n] = W1[((size_t)(b-bbase)*64 + k)*NT + n0 + n];
    }
    {
      const float4* xb4 = (const float4*)xb;
      #pragma unroll
      for (int r=0;r<5;r++){
        const int i = t + r*256;
        const int pos = i>>4, q4 = i&15;
        const float4 v = xb4[(size_t)idxC[pos]*16 + q4];
        smC[C_NBRS + (q4*4+0)*82 + pos] = v.x;
        smC[C_NBRS + (q4*4+1)*82 + pos] = v.y;
        smC[C_NBRS + (q4*4+2)*82 + pos] = v.z;
        smC[C_NBRS + (q4*4+3)*82 + pos] = v.w;
      }
    }
    __syncthreads();

    float accw[4][5] = {}, acch[4][5] = {};
    #pragma unroll 2
    for (int k=0;k<64;k++){
      float4 a4 = *(const float4*)&smC[C_WC2T + k*68 + tmv*4];
      float4 x4 = *(const float4*)&smC[C_XCDT + k*68 + tmv*4];
      const float av[4] = {a4.x,a4.y,a4.z,a4.w};
      const float xv[4] = {x4.x,x4.y,x4.z,x4.w};
      float bw[5], bh[5];
      #pragma unroll
      for (int j=0;j<5;j++){
        bw[j] = smC[C_W1S  + k*82 + tnv5 + j];
        bh[j] = smC[C_NBRS + k*82 + tnv5 + j];
      }
      #pragma unroll
      for (int i2=0;i2<4;i2++)
        #pragma unroll
        for (int j=0;j<5;j++){ accw[i2][j]+=av[i2]*bw[j]; acch[i2][j]+=xv[i2]*bh[j]; }
    }

    float hwreg[4][5];
    #pragma unroll
    for (int i2=0;i2<4;i2++){
      const int c = ch*64 + tmv*4 + i2;
      const float s2 = bn2g[c]*rs, b2 = bn2b[c], cb2 = wcb2[c];
      const float sx = xbng[c]*rs, bx = xbnb[c], cbx = xcb[c];
      const float hcc = HCC[((size_t)b*128 + c)*NPTS + p0 + p_loc];
      float w2[5], hv[5];
      #pragma unroll
      for (int j=0;j<5;j++){
        w2[j] = lrelu((accw[i2][j] + cb2)*s2 + b2, 0.01f);
        hv[j] = lrelu((acch[i2][j] + hcc + cbx)*sx + bx, 0.01f);
      }
      float mx = w2[0];
      #pragma unroll
      for (int j=1;j<5;j++) mx = fmaxf(mx, w2[j]);
      mx = fmaxf(mx, __shfl_xor(mx, 1));
      float ssum = 0.f;
      #pragma unroll
      for (int j=0;j<5;j++){ w2[j] = expf(w2[j]-mx); ssum += w2[j]; }
      ssum += __shfl_xor(ssum, 1);
      const float inv = 1.f/ssum;
      #pragma unroll
      for (int j=0;j<5;j++) hwreg[i2][j] = hv[j]*(w2[j]*inv);
    }
    __syncthreads();

    #pragma unroll
    for (int i2=0;i2<4;i2++){
      const int cl = tmv*4 + i2;
      #pragma unroll
      for (int j=0;j<5;j++)
        smC[C_HW + p_loc*648 + cl*10 + jh5 + j] = hwreg[i2][j];
    }
    __syncthreads();

    for (int kc=0; kc<640; kc+=64){
      #pragma unroll
      for (int r=0;r<32;r++){
        const int i = t + r*256;
        const int oo = i>>6, kk = i&63;
        smC[C_OWL + oo*65 + kk] = oW[(size_t)oo*1280 + ch*640 + kc + kk];
      }
      __syncthreads();
      #pragma unroll 4
      for (int kk=0; kk<64; kk+=4){
        const float w0 = smC[C_OWL + o*65 + kk];
        const float w1v= smC[C_OWL + o*65 + kk+1];
        const float w2v= smC[C_OWL + o*65 + kk+2];
        const float w3v= smC[C_OWL + o*65 + kk+3];
        #pragma unroll
        for (int pp=0;pp<4;pp++){
          const float4 h4 = *(const float4*)&smC[C_HW + (phalf*4+pp)*648 + kc + kk];
          acc2[pp] += w0*h4.x + w1v*h4.y + w2v*h4.z + w3v*h4.w;
        }
      }
      __syncthreads();
    }
  }
  const float obv = ob[o];
  #pragma unroll
  for (int pp=0;pp<4;pp++)
    X2[((size_t)b*128 + o)*NPTS + p0 + phalf*4 + pp] = acc2[pp] + obv;
}

// ---------------------------------------------------------------------------
template<int CH>
__global__ __launch_bounds__(256) void adain_kernel(
    float* __restrict__ X, const float* __restrict__ S)
{
  const int c = blockIdx.x, b = blockIdx.y;
  const int t = threadIdx.x;
  const size_t base = ((size_t)b*CH + c)*NPTS;
  __shared__ float red[256];
  float v[8];
  float s = 0.f;
  #pragma unroll
  for (int i=0;i<8;i++){
    float xv = X[base + t + i*256];
    xv = lrelu(xv, 0.2f);
    v[i] = xv; s += xv;
  }
  red[t] = s; __syncthreads();
  for (int st=128; st>0; st>>=1){ if (t<st) red[t] += red[t+st]; __syncthreads(); }
  const float mean = red[0]*(1.f/NPTS);
  __syncthreads();
  float s2 = 0.f;
  #pragma unroll
  for (int i=0;i<8;i++){ const float d = v[i]-mean; s2 += d*d; }
  red[t] = s2; __syncthreads();
  for (int st=128; st>0; st>>=1){ if (t<st) red[t] += red[t+st]; __syncthreads(); }
  const float var  = red[0]*(1.f/NPTS);
  const float rstd = 1.f/sqrtf(var + 1e-5f);
  const float* g  = S + ((size_t)b*2*CH + c)*NPTS;
  const float* be = S + ((size_t)b*2*CH + CH + c)*NPTS;
  #pragma unroll
  for (int i=0;i<8;i++){
    const int n = t + i*256;
    X[base+n] = g[n]*((v[i]-mean)*rstd) + be[n];
  }
}

__global__ __launch_bounds__(256) void maxn_kernel(const float* __restrict__ X, float* __restrict__ FG)
{
  const int c = blockIdx.x, b = blockIdx.y;
  const int t = threadIdx.x;
  const float* p = X + ((size_t)b*128 + c)*NPTS;
  __shared__ float red[256];
  float m = -3.4e38f;
  for (int i=t; i<NPTS; i+=256) m = fmaxf(m, p[i]);
  red[t] = m; __syncthreads();
  for (int st=128; st>0; st>>=1){ if (t<st) red[t] = fmaxf(red[t], red[t+st]); __syncthreads(); }
  if (t == 0) FG[b*128+c] = red[0];
}

__global__ __launch_bounds__(512) void fc_kernel(
    const float* __restrict__ FG,
    const float* __restrict__ gW1, const float* __restrict__ gb1,
    const float* __restrict__ gbn1g, const float* __restrict__ gbn1b,
    const float* __restrict__ gW2, const float* __restrict__ gb2,
    const float* __restrict__ gbn2g, const float* __restrict__ gbn2b,
    const float* __restrict__ tW1, const float* __restrict__ tb1,
    float* __restrict__ FGP)
{
  const int b = blockIdx.x, t = threadIdx.x;
  __shared__ float fg[128], h1[128], h2[512];
  const float rs = 1.f/sqrtf(1.f + 1e-5f);
  if (t < 128) fg[t] = FG[b*128+t];
  __syncthreads();
  if (t < 128){
    float s = 0.f;
    for (int c=0;c<128;c++) s += gW1[t*128+c]*fg[c];
    s += gb1[t];
    s = s*(gbn1g[t]*rs) + gbn1b[t];
    h1[t] = lrelu(s, 0.01f);
  }
  __syncthreads();
  {
    float s = 0.f;
    for (int c=0;c<128;c++) s += gW2[t*128+c]*h1[c];
    s += gb2[t];
    s = s*(gbn2g[t]*rs) + gbn2b[t];
    h2[t] = lrelu(s, 0.01f);
  }
  __syncthreads();
  if (t < 256){
    float s = tb1[t];
    for (int c=0;c<512;c++) s += tW1[(size_t)t*640 + c]*h2[c];
    FGP[b*256+t] = s;
  }
}

__global__ __launch_bounds__(256) void t3_kernel(
    const float* __restrict__ T2, const float* __restrict__ tW3,
    const float* __restrict__ tb3, float* __restrict__ outp)
{
  __shared__ float w[192];
  const int t = threadIdx.x;
  if (t < 192) w[t] = tW3[t];
  __syncthreads();
  const int b = blockIdx.y;
  const int n = blockIdx.x*256 + t;
  float a0 = tb3[0], a1 = tb3[1], a2 = tb3[2];
  for (int c=0;c<64;c++){
    const float v = T2[((size_t)b*64+c)*NPTS + n];
    a0 += w[c]*v; a1 += w[64+c]*v; a2 += w[128+c]*v;
  }
  float* op = outp + ((size_t)b*NPTS + n)*3;
  op[0]=a0; op[1]=a1; op[2]=a2;
}

// ---------------------------------------------------------------------------
extern "C" void kernel_launch(void* const* d_in, const int* in_sizes, int n_in,
                              void* d_out, int out_size, void* d_ws, size_t ws_size,
                              hipStream_t stream)
{
  (void)in_sizes; (void)n_in; (void)out_size; (void)ws_size;
  const float* z    = (const float*)d_in[0];
  const float* x    = (const float*)d_in[1];
  const float* hW1  = (const float*)d_in[2];
  const float* hb1  = (const float*)d_in[3];
  const float* hW2  = (const float*)d_in[4];
  const float* hb2  = (const float*)d_in[5];
  const float* e1_wc1 = (const float*)d_in[6];
  const float* e1_wcb1= (const float*)d_in[7];
  const float* e1_bn1g= (const float*)d_in[8];
  const float* e1_bn1b= (const float*)d_in[9];
  const float* e1_wc2 = (const float*)d_in[10];
  const float* e1_wcb2= (const float*)d_in[11];
  const float* e1_bn2g= (const float*)d_in[12];
  const float* e1_bn2b= (const float*)d_in[13];
  const float* e1_xc  = (const float*)d_in[14];
  const float* e1_xcb = (const float*)d_in[15];
  const float* e1_xbng= (const float*)d_in[16];
  const float* e1_xbnb= (const float*)d_in[17];
  const float* e1_oW  = (const float*)d_in[18];
  const float* e1_ob  = (const float*)d_in[19];
  const float* a1_W   = (const float*)d_in[20];
  const float* a1_b   = (const float*)d_in[21];
  const float* e2_wc1 = (const float*)d_in[22];
  const float* e2_wcb1= (const float*)d_in[23];
  const float* e2_bn1g= (const float*)d_in[24];
  const float* e2_bn1b= (const float*)d_in[25];
  const float* e2_wc2 = (const float*)d_in[26];
  const float* e2_wcb2= (const float*)d_in[27];
  const float* e2_bn2g= (const float*)d_in[28];
  const float* e2_bn2b= (const float*)d_in[29];
  const float* e2_xc  = (const float*)d_in[30];
  const float* e2_xcb = (const float*)d_in[31];
  const float* e2_xbng= (const float*)d_in[32];
  const float* e2_xbnb= (const float*)d_in[33];
  const float* e2_oW  = (const float*)d_in[34];
  const float* e2_ob  = (const float*)d_in[35];
  const float* a2_W   = (const float*)d_in[36];
  const float* a2_b   = (const float*)d_in[37];
  const float* gW1    = (const float*)d_in[38];
  const float* gb1    = (const float*)d_in[39];
  const float* gbn1g  = (const float*)d_in[40];
  const float* gbn1b  = (const float*)d_in[41];
  const float* gW2    = (const float*)d_in[42];
  const float* gb2    = (const float*)d_in[43];
  const float* gbn2g  = (const float*)d_in[44];
  const float* gbn2b  = (const float*)d_in[45];
  const float* tW1    = (const float*)d_in[46];
  const float* tb1    = (const float*)d_in[47];
  const float* tW2    = (const float*)d_in[48];
  const float* tb2    = (const float*)d_in[49];
  const float* tW3    = (const float*)d_in[50];
  const float* tb3    = (const float*)d_in[51];
  float* out = (float*)d_out;
  float* ws  = (float*)d_ws;

  // workspace layout (float units) — total ~18.6M floats ≈ 74.4 MB
  size_t off = 0;
  float*  ST    = ws + off; off += (size_t)BATCH*128*NPTS;    // 2,097,152
  float*  Sbuf  = ws + off; off += (size_t)BATCH*256*NPTS;    // 4,194,304
  float*  X1f   = ws + off; off += (size_t)BATCH*NPTS*64;     // 1,048,576
  float*  X2    = ws + off; off += (size_t)BATCH*128*NPTS;    // 2,097,152
  float*  T1    = ws + off; off += (size_t)BATCH*256*NPTS;    // 4,194,304
  float*  T2    = ws + off; off += (size_t)BATCH*64*NPTS;     //   524,288
  int*    IDX   = (int*)(ws + off); off += (size_t)BATCH*NPTS*KNB;  // 163,840
  float*  OW1T  = ws + off; off += (size_t)64*64*KNB;         //  40,960
  float*  XN3f  = ws + off; off += (size_t)BATCH*NPTS;        //  16,384
  double* XN64  = (double*)(ws + off); off += (size_t)2*BATCH*NPTS; // 32,768
  float*  FG    = ws + off; off += (size_t)BATCH*128;
  float*  FGP   = ws + off; off += (size_t)BATCH*256;
  off = (off + 1) & ~(size_t)1;
  double* X1_64 = (double*)(ws + off); off += (size_t)2*BATCH*64*NPTS;  // 2,097,152 fl
  double* X1T64 = (double*)(ws + off); off += (size_t)2*BATCH*NPTS*64;  // 2,097,152 fl

  // aliases (time-disjoint; liveness table):
  //  - TOPD/TOPI: live only between knn_part3 and knn_merge (T1, Sbuf dead then)
  //  - TOPF: (float*)X1_64, 16384*8*16 = 2,097,152 fl exact fit; X1_64 dead
  //          after transpose_cast64 (refine reads X1T64, not X1_64)
  //  - TOPI2: (int*)T1; T1 dead between style head and kernelA
  //  - X1c = Sbuf[0:1M]: written by transpose_cast64, READ by kernelP — must
  //          not be clobbered until kernelP completes (R10 bug: TOPI2 on Sbuf)
  double* TOPD  = (double*)T1;
  int*    TOPI  = (int*)Sbuf;
  float*  TOPF  = (float*)X1_64;
  int*    TOPI2 = (int*)T1;
  float*  X1c   = Sbuf;                 // (B,64,N) f32 chan-major
  float*  WCC   = Sbuf + 1048576;       // (B,64,N)
  float*  HCC   = Sbuf + 2097152;       // (B,128,N)
  float*  W1    = T1;                   // 2 batches x [64][NT] (after refine)

  // oW transpose for edge1
  owt_kernel<64><<<(64*64*KNB+255)/256, 256, 0, stream>>>(e1_oW, OW1T);

  // style head (np-exact f32)
  head1_exact<<<dim3(32,2,8), 256, 0, stream>>>(x, z, hW1, hb1, T1);
  gemm_bn<128,128,true><<<dim3(NPTS/128,1,8), 256, 0, stream>>>(
      T1, NPTS, (size_t)128*NPTS, 0, hW2, 128, 0, hb2, nullptr, nullptr, nullptr, 0,
      ST, NPTS, (size_t)128*NPTS, 128, 1, 0.01f, 0);

  // edge block 1
  norms3_f32<<<64, 256, 0, stream>>>(x, XN3f);
  knn_part3<<<512, 256, 0, stream>>>(x, XN3f, TOPD, TOPI);
  knn_merge_kernel<<<64, 256, 0, stream>>>(TOPD, TOPI, IDX);
  edge1_f64<<<2048, 512, 0, stream>>>(
      x, IDX, e1_wc1, e1_wcb1, e1_bn1g, e1_bn1b, e1_wc2, e1_wcb2, e1_bn2g, e1_bn2b,
      e1_xc, e1_xcb, e1_xbng, e1_xbnb, OW1T, e1_ob, X1_64);
  gemm_bn<128,128,true><<<dim3(NPTS/128,1,8), 256, 0, stream>>>(
      ST, NPTS, (size_t)128*NPTS, 0, a1_W, 128, 0, a1_b, nullptr, nullptr, nullptr, 0,
      Sbuf, NPTS, (size_t)128*NPTS, 128, 0, 0.f, 0);
  adain1_f64<<<dim3(64,8), 256, 0, stream>>>(X1_64, Sbuf);

  // x1 -> n-major f64 + f32, chan-major f32
  transpose_cast64<<<dim3(32,8), 256, 0, stream>>>(X1_64, X1T64, X1f, X1c);

  // block2 kNN: f32 coarse (LDS-tiled, double-buffered) + f64 refine
  norms64_f32<<<64, 256, 0, stream>>>(X1f, XN3f);
  norms64d<<<64, 256, 0, stream>>>(X1T64, XN64);
  knn_coarse<<<512, 256, 0, stream>>>(X1f, XN3f, TOPF, TOPI2);
  knn_refine<<<64, 256, 0, stream>>>(TOPF, TOPI2, X1T64, XN64, IDX);

  // edge block 2 pipeline
  kernelP<<<dim3(16,3,8), 256, 0, stream>>>(X1c, e2_wc1, e2_xc, WCC, HCC);
  for (int lb=0; lb<4; lb++){
    const int bbase = lb*2;
    kernelA<<<dim3(NT/128,1,2), 256, 0, stream>>>(
        X1f, IDX, WCC, e2_wc1, e2_wcb1, e2_bn1g, e2_bn1b, W1, bbase);
    kernelC<<<dim3(NT/80,1,2), 256, 0, stream>>>(
        X1f, IDX, W1, HCC, e2_wc2, e2_wcb2, e2_bn2g, e2_bn2b,
        e2_xc, e2_xcb, e2_xbng, e2_xbnb, e2_oW, e2_ob, X2, bbase);
  }

  // adain2
  gemm_bn<128,128><<<dim3(NPTS/128,2,8), 256, 0, stream>>>(
      ST, NPTS, (size_t)128*NPTS, 0, a2_W, 128, 0, a2_b, nullptr, nullptr, nullptr, 0,
      Sbuf, NPTS, (size_t)256*NPTS, 128, 0, 0.f, 0);
  adain_kernel<128><<<dim3(128,8), 256, 0, stream>>>(X2, Sbuf);

  // global feature + final MLP
  maxn_kernel<<<dim3(128,8), 256, 0, stream>>>(X2, FG);
  fc_kernel<<<8, 512, 0, stream>>>(FG, gW1, gb1, gbn1g, gbn1b, gW2, gb2, gbn2g, gbn2b, tW1, tb1, FGP);
  gemm_bn<128,128><<<dim3(NPTS/128,2,8), 256, 0, stream>>>(
      X2, NPTS, (size_t)128*NPTS, 0, tW1, 640, 512, nullptr, nullptr, nullptr, FGP, 256,
      T1, NPTS, (size_t)256*NPTS, 128, 1, 0.01f, 0);
  gemm_bn<64,128><<<dim3(NPTS/128,1,8), 256, 0, stream>>>(
      T1, NPTS, (size_t)256*NPTS, 0, tW2, 256, 0, tb2, nullptr, nullptr, nullptr, 0,
      T2, NPTS, (size_t)64*NPTS, 256, 1, 0.01f, 0);
  t3_kernel<<<dim3(8,8), 256, 0, stream>>>(T2, tW3, tb3, out);
}

// Round 12
// 1558.667 us; speedup vs baseline: 1.0097x; 1.0097x over previous
//
#include <hip/hip_runtime.h>
#include <math.h>

#define NPTS 2048
#define BATCH 8
#define KNB 10
#define NT (NPTS*KNB)   // 20480 positions per batch (point*10+j)

static __device__ __forceinline__ float lrelu(float x, float s){ return x >= 0.f ? x : s*x; }
static __device__ __forceinline__ double lrelu_d(double x, double s){ return x >= 0.0 ? x : s*x; }

// ---------------------------------------------------------------------------
// Tiled GEMM with fused epilogue. EXACT=true bit-matches numpy einsum
// 'bcn,oc->bon' (+bias, opt lrelu): single f32 acc, ascending k, no FMA.
// ---------------------------------------------------------------------------
template<int TM, int TN, bool EXACT=false>
__global__ __launch_bounds__(256) void gemm_bn(
    const float* __restrict__ In, int ldn, size_t inBS, int koff,
    const float* __restrict__ W, int wstride, int wcol0,
    const float* __restrict__ cb, const float* __restrict__ bng, const float* __restrict__ bnb,
    const float* __restrict__ addBO, int addM,
    float* __restrict__ Out, int ldo, size_t outBS,
    int C, int act, float neg, int bbase)
{
  constexpr int RM = TM/16, RN = TN/16;
  __shared__ float As[16][TM+4];
  __shared__ float Bs[16][TN+4];
  const int b = bbase + blockIdx.z;
  const float* in = In + (size_t)b*inBS;
  float* outp = Out + (size_t)b*outBS;
  const int m0 = blockIdx.y*TM, n0 = blockIdx.x*TN;
  const int t = threadIdx.x;
  const int tmv = t>>4, tnv = t&15;
  float acc[RM][RN] = {};
  for (int k0=0; k0<C; k0+=16){
    #pragma unroll
    for (int s=0;s<RM;s++){
      const int i = t + s*256;
      const int k = i&15, m = i>>4;
      As[k][m] = W[(size_t)(m0+m)*wstride + wcol0 + k0 + k];
    }
    #pragma unroll
    for (int s=0;s<RN;s++){
      const int i = t + s*256;
      const int n = i & (TN-1), kk2 = i / TN;
      Bs[kk2][n] = in[(size_t)(koff + k0 + kk2)*ldn + n0 + n];
    }
    __syncthreads();
    #pragma unroll
    for (int kk=0;kk<16;kk++){
      float av[RM], bv[RN];
      #pragma unroll
      for (int s=0;s<RM/4;s++){
        float4 v = *(const float4*)&As[kk][tmv*RM + s*4];
        av[s*4]=v.x; av[s*4+1]=v.y; av[s*4+2]=v.z; av[s*4+3]=v.w;
      }
      #pragma unroll
      for (int s=0;s<RN/4;s++){
        float4 v = *(const float4*)&Bs[kk][tnv*RN + s*4];
        bv[s*4]=v.x; bv[s*4+1]=v.y; bv[s*4+2]=v.z; bv[s*4+3]=v.w;
      }
      #pragma unroll
      for (int i2=0;i2<RM;i2++)
        #pragma unroll
        for (int j2=0;j2<RN;j2++){
          if constexpr (EXACT)
            acc[i2][j2] = __fadd_rn(acc[i2][j2], __fmul_rn(av[i2], bv[j2]));
          else
            acc[i2][j2] += av[i2]*bv[j2];
        }
    }
    __syncthreads();
  }
  const float rs = 1.f/sqrtf(1.f + 1e-5f);
  #pragma unroll
  for (int i2=0;i2<RM;i2++){
    const int gm = m0 + tmv*RM + i2;
    float addv = cb ? cb[gm] : 0.f;
    if (addBO) addv += addBO[b*addM + gm];
    float sc = 1.f, bs = 0.f;
    if (bng){ sc = bng[gm]*rs; bs = bnb[gm]; }
    float* orow = outp + (size_t)gm*ldo + n0 + tnv*RN;
    #pragma unroll
    for (int j4=0;j4<RN/4;j4++){
      float4 o;
      float vv[4];
      #pragma unroll
      for (int q=0;q<4;q++){
        float v;
        if constexpr (EXACT){
          v = __fadd_rn(acc[i2][j4*4+q], addv);
          if (act) v = (v >= 0.f) ? v : __fmul_rn(neg, v);
        } else {
          v = acc[i2][j4*4+q] + addv;
          if (bng) v = v*sc + bs;
          if (act) v = lrelu(v, neg);
        }
        vv[q] = v;
      }
      o.x=vv[0]; o.y=vv[1]; o.z=vv[2]; o.w=vv[3];
      *(float4*)&orow[j4*4] = o;
    }
  }
}

// ---------------------------------------------------------------------------
// Head layer 1 (EXACT): C=131 gathered from x (B,N,3), z (B,N,128); lrelu 0.01
// ---------------------------------------------------------------------------
__global__ __launch_bounds__(256) void head1_exact(
    const float* __restrict__ x, const float* __restrict__ z,
    const float* __restrict__ W, const float* __restrict__ bias,
    float* __restrict__ outh)
{
  __shared__ float As[16][68];
  __shared__ float Bs[16][68];
  const int b = blockIdx.z;
  const int m0 = blockIdx.y*64, n0 = blockIdx.x*64;
  const int t = threadIdx.x;
  const int tm = t>>4, tn = t&15;
  float acc[4][4] = {};
  for (int k0 = 0; k0 < 144; k0 += 16){
    #pragma unroll
    for (int i=0;i<4;i++){
      const int ii = t + i*256;
      const int k = ii&15, m = ii>>4;
      const int gk = k0+k;
      As[k][m] = (gk<131) ? W[(size_t)(m0+m)*131 + gk] : 0.f;
    }
    #pragma unroll
    for (int i=0;i<4;i++){
      const int ii = t + i*256;
      const int k = ii&15, nn = ii>>4;
      const int gk = k0+k, gn = n0+nn;
      float v = 0.f;
      if (gk < 3)        v = x[((size_t)b*NPTS+gn)*3   + gk];
      else if (gk < 131) v = z[((size_t)b*NPTS+gn)*128 + (gk-3)];
      Bs[k][nn] = v;
    }
    __syncthreads();
    #pragma unroll
    for (int k=0;k<16;k++){
      #pragma unroll
      for (int i=0;i<4;i++){
        const float a = As[k][tm*4+i];
        #pragma unroll
        for (int j=0;j<4;j++){
          acc[i][j] = __fadd_rn(acc[i][j], __fmul_rn(a, Bs[k][tn*4+j]));
        }
      }
    }
    __syncthreads();
  }
  #pragma unroll
  for (int i=0;i<4;i++){
    const int gm = m0 + tm*4 + i;
    #pragma unroll
    for (int j=0;j<4;j++){
      float v = __fadd_rn(acc[i][j], bias[gm]);
      v = (v >= 0.f) ? v : __fmul_rn(0.01f, v);
      outh[((size_t)b*128+gm)*NPTS + n0 + tn*4 + j] = v;
    }
  }
}

// ---------------------------------------------------------------------------
// Block-1 kNN: f32 np-exact.
// ---------------------------------------------------------------------------
__global__ __launch_bounds__(256) void norms3_f32(const float* __restrict__ Xn, float* __restrict__ XN)
{
  const int q = blockIdx.x*256 + threadIdx.x;
  const float* p = Xn + (size_t)q*3;
  float s = __fmul_rn(p[0],p[0]);
  s = __fadd_rn(s, __fmul_rn(p[1],p[1]));
  s = __fadd_rn(s, __fmul_rn(p[2],p[2]));
  XN[q] = s;
}

__global__ __launch_bounds__(256) void knn_part3(
    const float* __restrict__ Xn, const float* __restrict__ XN,
    double* __restrict__ topd, int* __restrict__ topi)
{
  const int t = threadIdx.x;
  const int qloc = t & 31, part = t >> 5;
  const int q = blockIdx.x*32 + qloc;
  const int b = q >> 11, n = q & (NPTS-1);
  const float* xb = Xn + (size_t)b*NPTS*3;
  const float qx = xb[(size_t)n*3+0], qy = xb[(size_t)n*3+1], qz = xb[(size_t)n*3+2];
  const float qn = XN[q];
  float td[11]; int ti[11];
  #pragma unroll
  for (int r=0;r<11;r++){ td[r] = 3.4e38f; ti[r] = 0x7fffffff; }
  const int m0 = part*(NPTS/8);
  for (int mm=0; mm<NPTS/8; mm++){
    const int m = m0 + mm;
    float dot = __fmul_rn(qx, xb[(size_t)m*3+0]);
    dot = __fadd_rn(dot, __fmul_rn(qy, xb[(size_t)m*3+1]));
    dot = __fadd_rn(dot, __fmul_rn(qz, xb[(size_t)m*3+2]));
    float dist = __fmul_rn(-2.f, dot);
    dist = __fadd_rn(dist, qn);
    dist = __fadd_rn(dist, XN[b*NPTS + m]);
    if (dist < td[10]){
      td[10] = dist; ti[10] = m;
      #pragma unroll
      for (int p=10;p>0;p--){
        if (td[p] < td[p-1]){
          float tf=td[p]; td[p]=td[p-1]; td[p-1]=tf;
          int   tt=ti[p]; ti[p]=ti[p-1]; ti[p-1]=tt;
        }
      }
    }
  }
  const size_t base = ((size_t)q*8 + part)*11;
  #pragma unroll
  for (int r=0;r<11;r++){ topd[base+r] = (double)td[r]; topi[base+r] = ti[r]; }
}

__global__ __launch_bounds__(256) void knn_merge_kernel(
    const double* __restrict__ topd, const int* __restrict__ topi, int* __restrict__ idxout)
{
  const int q = blockIdx.x*256 + threadIdx.x;
  double td[11]; int ti[11];
  #pragma unroll
  for (int r=0;r<11;r++){ td[r] = 1.0e308; ti[r] = 0x7fffffff; }
  const size_t base = (size_t)q*88;
  for (int s=0; s<88; s++){
    const double d = topd[base+s];
    const int  im = topi[base+s];
    if (d < td[10] || (d == td[10] && im < ti[10])){
      td[10] = d; ti[10] = im;
      #pragma unroll
      for (int p=10;p>0;p--){
        const bool sw = (td[p] < td[p-1]) || (td[p] == td[p-1] && ti[p] < ti[p-1]);
        if (sw){
          double tf=td[p]; td[p]=td[p-1]; td[p-1]=tf;
          int    tt=ti[p]; ti[p]=ti[p-1]; ti[p-1]=tt;
        }
      }
    }
  }
  #pragma unroll
  for (int j=0;j<KNB;j++) idxout[(size_t)q*KNB + j] = ti[j+1];
}

// ---------------------------------------------------------------------------
// Block-2 kNN stage 1: LDS-tiled candidates + in-register top-16 (R9 proven).
// Block = 32 queries; thread (q,p): list p owns candidates m%8==p, ascending.
// ---------------------------------------------------------------------------
__global__ __launch_bounds__(256) void norms64_f32(const float* __restrict__ Xn, float* __restrict__ XN)
{
  const int q = blockIdx.x*256 + threadIdx.x;
  const float4* p4 = (const float4*)(Xn + (size_t)q*64);
  float s0=0.f,s1=0.f,s2=0.f,s3=0.f;
  #pragma unroll
  for (int d4=0; d4<16; d4++){
    float4 v = p4[d4];
    s0 += v.x*v.x; s1 += v.y*v.y; s2 += v.z*v.z; s3 += v.w*v.w;
  }
  XN[q] = (s0+s1)+(s2+s3);
}

__global__ __launch_bounds__(256) void knn_coarse(
    const float* __restrict__ Xn, const float* __restrict__ XN,
    float* __restrict__ topf, int* __restrict__ topi)
{
  __shared__ float Cs[64][68];
  __shared__ float xns[64];
  const int t = threadIdx.x;
  const int tq = t>>3, p = t&7;
  const int q0 = blockIdx.x*32;
  const int b  = q0 >> 11;
  const int gq = q0 + tq;
  const int nloc = (q0 & (NPTS-1)) + tq;
  const float* xb = Xn + (size_t)b*NPTS*64;
  float qv[64];
  {
    const float4* p4 = (const float4*)(xb + (size_t)nloc*64);
    #pragma unroll
    for (int d4=0; d4<16; d4++){ float4 v = p4[d4]; qv[d4*4]=v.x; qv[d4*4+1]=v.y; qv[d4*4+2]=v.z; qv[d4*4+3]=v.w; }
  }
  const float qn = XN[gq];
  float td[16]; int ti[16];
  #pragma unroll
  for (int r=0;r<16;r++){ td[r] = 3.4e38f; ti[r] = 0x7fffffff; }

  for (int m0=0; m0<NPTS; m0+=64){
    __syncthreads();
    #pragma unroll
    for (int s=0;s<4;s++){
      const int i = t + s*256;
      const int row = i>>4, f4 = i&15;
      float4 v = *(const float4*)(xb + (size_t)(m0+row)*64 + f4*4);
      *(float4*)&Cs[row][f4*4] = v;
    }
    if (t < 64) xns[t] = XN[b*NPTS + m0 + t];
    __syncthreads();
    #pragma unroll
    for (int jj=0;jj<8;jj++){
      const int row = jj*8 + p;
      float d0=0.f,d1=0.f,d2=0.f,d3=0.f;
      #pragma unroll
      for (int k4=0;k4<16;k4++){
        float4 v = *(const float4*)&Cs[row][k4*4];
        d0 += qv[k4*4+0]*v.x; d1 += qv[k4*4+1]*v.y;
        d2 += qv[k4*4+2]*v.z; d3 += qv[k4*4+3]*v.w;
      }
      const float dist = qn - 2.f*((d0+d1)+(d2+d3)) + xns[row];
      const int m = m0 + row;
      if (dist < td[15]){
        td[15] = dist; ti[15] = m;
        #pragma unroll
        for (int pp=15;pp>0;pp--){
          if (td[pp] < td[pp-1]){
            float tf=td[pp]; td[pp]=td[pp-1]; td[pp-1]=tf;
            int   tt=ti[pp]; ti[pp]=ti[pp-1]; ti[pp-1]=tt;
          }
        }
      }
    }
  }
  const size_t base = ((size_t)gq*8 + p)*16;
  #pragma unroll
  for (int r=0;r<16;r++){ topf[base+r] = td[r]; topi[base+r] = ti[r]; }
}

// ---------------------------------------------------------------------------
// Block-2 kNN stage 2: merge 8x16 -> f32 top-16, f64 re-rank, emit 10.
// ---------------------------------------------------------------------------
__global__ __launch_bounds__(256) void norms64d(const double* __restrict__ Xn, double* __restrict__ XN)
{
  const int q = blockIdx.x*256 + threadIdx.x;
  const double* p = Xn + (size_t)q*64;
  double s = 0.0;
  #pragma unroll
  for (int d=0; d<64; d++) s += p[d]*p[d];
  XN[q] = s;
}

__global__ __launch_bounds__(256) void knn_refine(
    const float* __restrict__ topf, const int* __restrict__ topi,
    const double* __restrict__ Xd, const double* __restrict__ XNd,
    int* __restrict__ idxout)
{
  const int q = blockIdx.x*256 + threadIdx.x;
  const int b = q >> 11;
  float tf[16]; int ti[16];
  #pragma unroll
  for (int r=0;r<16;r++){ tf[r] = 3.4e38f; ti[r] = 0x7fffffff; }
  const size_t base = (size_t)q*128;
  for (int s=0; s<128; s++){
    const float d = topf[base+s];
    const int  im = topi[base+s];
    if (d < tf[15] || (d == tf[15] && im < ti[15])){
      tf[15] = d; ti[15] = im;
      #pragma unroll
      for (int p=15;p>0;p--){
        const bool sw = (tf[p] < tf[p-1]) || (tf[p] == tf[p-1] && ti[p] < ti[p-1]);
        if (sw){
          float a=tf[p]; tf[p]=tf[p-1]; tf[p-1]=a;
          int   c=ti[p]; ti[p]=ti[p-1]; ti[p-1]=c;
        }
      }
    }
  }
  double qv[64];
  {
    const double2* p2 = (const double2*)(Xd + (size_t)q*64);
    #pragma unroll
    for (int d2=0; d2<32; d2++){ double2 v = p2[d2]; qv[d2*2]=v.x; qv[d2*2+1]=v.y; }
  }
  const double qn = XNd[q];
  double dd[11]; int di[11];
  #pragma unroll
  for (int r=0;r<11;r++){ dd[r] = 1.0e308; di[r] = 0x7fffffff; }
  for (int s=0; s<16; s++){
    const int m = ti[s];
    const double2* c2 = (const double2*)(Xd + ((size_t)(b*NPTS + m))*64);
    double d0=0.0,d1=0.0,d2s=0.0,d3=0.0;
    #pragma unroll
    for (int d4=0; d4<16; d4++){
      double2 va = c2[d4*2], vb = c2[d4*2+1];
      d0 += qv[d4*4+0]*va.x; d1 += qv[d4*4+1]*va.y;
      d2s+= qv[d4*4+2]*vb.x; d3 += qv[d4*4+3]*vb.y;
    }
    const double dot = (d0+d1)+(d2s+d3);
    const double dist = (qn - 2.0*dot) + XNd[b*NPTS + m];
    if (dist < dd[10] || (dist == dd[10] && m < di[10])){
      dd[10] = dist; di[10] = m;
      #pragma unroll
      for (int p=10;p>0;p--){
        const bool sw = (dd[p] < dd[p-1]) || (dd[p] == dd[p-1] && di[p] < di[p-1]);
        if (sw){
          double a=dd[p]; dd[p]=dd[p-1]; dd[p-1]=a;
          int    c=di[p]; di[p]=di[p-1]; di[p-1]=c;
        }
      }
    }
  }
  #pragma unroll
  for (int j=0;j<KNB;j++) idxout[(size_t)q*KNB + j] = di[j+1];
}

// ---------------------------------------------------------------------------
// Edge block 1 (mixed precision, np-matched) — register-ized (R9, proven).
// ---------------------------------------------------------------------------
__global__ __launch_bounds__(512) void edge1_f64(
    const float* __restrict__ Xn, const int* __restrict__ idx,
    const float* __restrict__ wc1, const float* __restrict__ wcb1,
    const float* __restrict__ bn1g, const float* __restrict__ bn1b,
    const float* __restrict__ wc2, const float* __restrict__ wcb2,
    const float* __restrict__ bn2g, const float* __restrict__ bn2b,
    const float* __restrict__ xc,  const float* __restrict__ xcb,
    const float* __restrict__ xbng, const float* __restrict__ xbnb,
    const float* __restrict__ oWT, const float* __restrict__ ob,
    double* __restrict__ outX)
{
  __shared__ double w1bd[8][32];
  __shared__ float smw2[4096];
  __shared__ double hwbd[8][64];

  const int t = threadIdx.x;
  const int wid = t>>6, lane = t&63;
  const double sq = sqrt(1.0 + 1e-5);
  const int m31 = lane & 31;

  float wc1row[3];
  wc1row[0] = wc1[m31*3+0]; wc1row[1] = wc1[m31*3+1]; wc1row[2] = wc1[m31*3+2];
  const float wcb1r = wcb1[m31];
  const double fs1r = (double)bn1g[m31]/sq, fb1r = (double)bn1b[m31];
  float wc2row[32];
  #pragma unroll
  for (int m=0;m<32;m++) wc2row[m] = wc2[lane*32 + m];
  const float wcb2r = wcb2[lane];
  const double fs2r = (double)bn2g[lane]/sq, fb2r = (double)bn2b[lane];
  float xcrow[6];
  #pragma unroll
  for (int c=0;c<6;c++) xcrow[c] = xc[lane*6 + c];
  const float xcbr = xcb[lane];
  const double fsxr = (double)xbng[lane]/sq, fbxr = (double)xbnb[lane];

  const int p = blockIdx.x*8 + wid;
  const int b = p >> 11, n = p & (NPTS-1);
  const float* xb = Xn + (size_t)b*NPTS*3;
  const float cen0 = xb[(size_t)n*3+0];
  const float cen1 = xb[(size_t)n*3+1];
  const float cen2 = xb[(size_t)n*3+2];
  const int* ip = idx + ((size_t)b*NPTS + n)*KNB;

  double w2r[KNB], hr[KNB];
  #pragma unroll
  for (int j=0;j<KNB;j++){
    const int id = ip[j];
    const float dif0 = __fadd_rn(xb[(size_t)id*3+0], -cen0);
    const float dif1 = __fadd_rn(xb[(size_t)id*3+1], -cen1);
    const float dif2 = __fadd_rn(xb[(size_t)id*3+2], -cen2);
    {
      float s = __fmul_rn(wc1row[0], dif0);
      s = __fadd_rn(s, __fmul_rn(wc1row[1], dif1));
      s = __fadd_rn(s, __fmul_rn(wc1row[2], dif2));
      s = __fadd_rn(s, wcb1r);
      const double w1v = lrelu_d((double)s * fs1r + fb1r, 0.01);
      if (lane < 32) w1bd[wid][lane] = w1v;
    }
    __builtin_amdgcn_wave_barrier();
    {
      double s2 = 0.0;
      #pragma unroll 8
      for (int m=0;m<32;m++) s2 += (double)wc2row[m] * w1bd[wid][m];
      s2 += (double)wcb2r;
      w2r[j] = lrelu_d(s2*fs2r + fb2r, 0.01);
    }
    {
      float s3 = __fmul_rn(xcrow[0], cen0);
      s3 = __fadd_rn(s3, __fmul_rn(xcrow[1], cen1));
      s3 = __fadd_rn(s3, __fmul_rn(xcrow[2], cen2));
      s3 = __fadd_rn(s3, __fmul_rn(xcrow[3], dif0));
      s3 = __fadd_rn(s3, __fmul_rn(xcrow[4], dif1));
      s3 = __fadd_rn(s3, __fmul_rn(xcrow[5], dif2));
      s3 = __fadd_rn(s3, xcbr);
      hr[j] = lrelu_d((double)s3*fsxr + fbxr, 0.01);
    }
    __builtin_amdgcn_wave_barrier();
  }

  double hw[KNB];
  {
    double mx = w2r[0];
    #pragma unroll
    for (int j=1;j<KNB;j++) mx = fmax(mx, w2r[j]);
    double ssum = 0.0;
    #pragma unroll
    for (int j=0;j<KNB;j++){ const double e = exp(w2r[j]-mx); w2r[j]=e; ssum+=e; }
    #pragma unroll
    for (int j=0;j<KNB;j++) hw[j] = hr[j]*(w2r[j]/ssum);
  }

  double acc = 0.0;
  #pragma unroll
  for (int j=0;j<KNB;j++){
    __syncthreads();
    for (int i=t; i<4096; i+=512) smw2[i] = oWT[(size_t)j*4096 + i];
    hwbd[wid][lane] = hw[j];
    __syncthreads();
    double s = 0.0;
    #pragma unroll 8
    for (int c=0;c<64;c++) s += (double)smw2[c*64 + lane]*hwbd[wid][c];
    acc += s;
  }
  outX[((size_t)b*64+lane)*NPTS + n] = acc + (double)ob[lane];
}

template<int CH>
__global__ void owt_kernel(const float* __restrict__ oW, float* __restrict__ oWT)
{
  const int i = blockIdx.x*256 + threadIdx.x;
  if (i < CH*CH*KNB){
    const int j  = i % KNB;
    const int c2 = (i / KNB) % CH;
    const int o  = i / (KNB*CH);
    oWT[((size_t)j*CH + c2)*CH + o] = oW[i];
  }
}

__global__ __launch_bounds__(256) void adain1_f64(
    double* __restrict__ X, const float* __restrict__ S)
{
  const int c = blockIdx.x, b = blockIdx.y;
  const int t = threadIdx.x;
  const size_t base = ((size_t)b*64 + c)*NPTS;
  __shared__ double red[256];
  double v[8];
  double s = 0.0;
  #pragma unroll
  for (int i=0;i<8;i++){
    double xv = X[base + t + i*256];
    xv = lrelu_d(xv, 0.2);
    v[i] = xv; s += xv;
  }
  red[t] = s; __syncthreads();
  for (int st=128; st>0; st>>=1){ if (t<st) red[t] += red[t+st]; __syncthreads(); }
  const double mean = red[0]/(double)NPTS;
  __syncthreads();
  double s2 = 0.0;
  #pragma unroll
  for (int i=0;i<8;i++){ const double d = v[i]-mean; s2 += d*d; }
  red[t] = s2; __syncthreads();
  for (int st=128; st>0; st>>=1){ if (t<st) red[t] += red[t+st]; __syncthreads(); }
  const double var  = red[0]/(double)NPTS;
  const double rstd = 1.0/sqrt(var + 1e-5);
  const float* g  = S + ((size_t)b*128 + c)*NPTS;
  const float* be = S + ((size_t)b*128 + 64 + c)*NPTS;
  #pragma unroll
  for (int i=0;i<8;i++){
    const int n = t + i*256;
    X[base+n] = (double)g[n]*((v[i]-mean)*rstd) + (double)be[n];
  }
}

// (B,64,N) f64 chan-major -> X1T64 (B,N,64) f64, X1f (B,N,64) f32, X1c (B,64,N) f32
__global__ __launch_bounds__(256) void transpose_cast64(
    const double* __restrict__ in, double* __restrict__ outT,
    float* __restrict__ outTf, float* __restrict__ outC)
{
  __shared__ double tile[64][65];
  const int b = blockIdx.y, n0 = blockIdx.x*64;
  const int t = threadIdx.x;
  for (int i=t; i<4096; i+=256){
    const int n=i&63, c=i>>6;
    const double v = in[((size_t)b*64+c)*NPTS + n0+n];
    tile[c][n] = v;
    outC[((size_t)b*64+c)*NPTS + n0+n] = (float)v;
  }
  __syncthreads();
  for (int i=t; i<4096; i+=256){
    const int c=i&63, n=i>>6;
    const double v = tile[c][n];
    outT [((size_t)b*NPTS+n0+n)*64 + c] = v;
    outTf[((size_t)b*NPTS+n0+n)*64 + c] = (float)v;
  }
}

// ---------------------------------------------------------------------------
// Kernel P: per-point center GEMMs (WCC, HCC).
// ---------------------------------------------------------------------------
__global__ __launch_bounds__(256) void kernelP(
    const float* __restrict__ x1c, const float* __restrict__ wc1,
    const float* __restrict__ xc,
    float* __restrict__ WCC, float* __restrict__ HCC)
{
  __shared__ float As[16][68];
  __shared__ float Bs[16][132];
  const int b = blockIdx.z;
  const int y = blockIdx.y;
  const int n0 = blockIdx.x*128;
  const int t = threadIdx.x;
  const int tm = t>>4, tn = t&15;
  float acc[4][8] = {};
  for (int k0=0; k0<64; k0+=16){
    #pragma unroll
    for (int s=0;s<4;s++){
      const int i = t + s*256;
      const int k = i&15, m = i>>4;
      float w;
      if (y == 0) w = wc1[(size_t)m*64 + k0 + k];
      else {
        const int c = (y-1)*64 + m;
        w = xc[(size_t)c*128 + k0 + k] - xc[(size_t)c*128 + 64 + k0 + k];
      }
      As[k][m] = w;
    }
    #pragma unroll
    for (int s=0;s<8;s++){
      const int i = t + s*256;
      const int n = i&127, kk = i>>7;
      Bs[kk][n] = x1c[((size_t)b*64 + k0 + kk)*NPTS + n0 + n];
    }
    __syncthreads();
    #pragma unroll
    for (int k=0;k<16;k++){
      float4 a4 = *(const float4*)&As[k][tm*4];
      const float av[4] = {a4.x, a4.y, a4.z, a4.w};
      #pragma unroll
      for (int j=0;j<8;j++){
        const float bv = Bs[k][tn + j*16];
        #pragma unroll
        for (int i2=0;i2<4;i2++) acc[i2][j] += av[i2]*bv;
      }
    }
    __syncthreads();
  }
  #pragma unroll
  for (int i2=0;i2<4;i2++){
    const int m = tm*4 + i2;
    #pragma unroll
    for (int j=0;j<8;j++){
      const int n = n0 + tn + j*16;
      if (y == 0) WCC[((size_t)b*64 + m)*NPTS + n] = acc[i2][j];
      else        HCC[((size_t)b*128 + (y-1)*64 + m)*NPTS + n] = acc[i2][j];
    }
  }
}

// ---------------------------------------------------------------------------
// Kernel A: w1 = lrelu(bn1( wc1@nbr - WCC + wcb1 ))
// ---------------------------------------------------------------------------
__global__ __launch_bounds__(256) void kernelA(
    const float* __restrict__ X1f, const int* __restrict__ IDX,
    const float* __restrict__ WCC,
    const float* __restrict__ wc1, const float* __restrict__ wcb1,
    const float* __restrict__ bn1g, const float* __restrict__ bn1b,
    float* __restrict__ W1, int bbase)
{
  __shared__ float wc1T[64*68];
  __shared__ float nbr[64*132];
  __shared__ int idx_l[128];
  const int b = bbase + blockIdx.z;
  const int n0 = blockIdx.x*128;
  const int t = threadIdx.x;
  const float* xb = X1f + (size_t)b*NPTS*64;

  if (t < 128){
    const int n = n0 + t;
    idx_l[t] = IDX[((size_t)b*NPTS + n/10)*KNB + (n%10)];
  }
  for (int i=t; i<4096; i+=256){
    const int k = i&63, m = i>>6;
    wc1T[k*68 + m] = wc1[(size_t)m*64 + k];
  }
  __syncthreads();
  const float4* xb4 = (const float4*)xb;
  #pragma unroll
  for (int r=0; r<8; r++){
    const int i = t + r*256;
    const int pos = i>>4, q4 = i&15;
    const float4 v = xb4[(size_t)idx_l[pos]*16 + q4];
    nbr[(q4*4+0)*132 + pos] = v.x;
    nbr[(q4*4+1)*132 + pos] = v.y;
    nbr[(q4*4+2)*132 + pos] = v.z;
    nbr[(q4*4+3)*132 + pos] = v.w;
  }
  __syncthreads();

  const int tm = t>>4, tn = t&15;
  float acc[4][8] = {};
  #pragma unroll 4
  for (int k=0;k<64;k++){
    float4 a4 = *(const float4*)&wc1T[k*68 + tm*4];
    const float av[4] = {a4.x, a4.y, a4.z, a4.w};
    #pragma unroll
    for (int j=0;j<8;j++){
      const float bv = nbr[k*132 + tn + j*16];
      #pragma unroll
      for (int i2=0;i2<4;i2++) acc[i2][j] += av[i2]*bv;
    }
  }
  const float rs = 1.f/sqrtf(1.f + 1e-5f);
  #pragma unroll
  for (int i2=0;i2<4;i2++){
    const int m = tm*4 + i2;
    const float bias = wcb1[m];
    const float sc = bn1g[m]*rs, bb = bn1b[m];
    #pragma unroll
    for (int j=0;j<8;j++){
      const int n = n0 + tn + j*16;
      const int p = n/10;
      float v = acc[i2][j] - WCC[((size_t)b*64 + m)*NPTS + p] + bias;
      v = lrelu(v*sc + bb, 0.01f);
      W1[((size_t)(b-bbase)*64 + m)*NT + n] = v;
    }
  }
}

// ---------------------------------------------------------------------------
// Kernel C (chunked channels: 2 x 64): fused w2-GEMM + h-GEMM + softmax +
// partial output einsum. LDS union 19200 floats (76.8 KB) -> 2 blocks/CU.
// ---------------------------------------------------------------------------
#define C_WC2T 0
#define C_XCDT 4352
#define C_W1S  8704
#define C_NBRS 13952
#define C_TOT  19200
#define C_HW   0       /* [8][648] = 5184 */
#define C_OWL  5184    /* [128][65] = 8320 -> end 13504 */

__global__ __launch_bounds__(256) void kernelC(
    const float* __restrict__ X1f, const int* __restrict__ IDX,
    const float* __restrict__ W1, const float* __restrict__ HCC,
    const float* __restrict__ wc2, const float* __restrict__ wcb2,
    const float* __restrict__ bn2g, const float* __restrict__ bn2b,
    const float* __restrict__ xc,  const float* __restrict__ xcb,
    const float* __restrict__ xbng, const float* __restrict__ xbnb,
    const float* __restrict__ oW, const float* __restrict__ ob,
    float* __restrict__ X2, int bbase)
{
  __shared__ float smC[C_TOT];
  __shared__ int idxC[80];
  const int b = bbase + blockIdx.z;
  const int n0 = blockIdx.x*80;
  const int p0 = n0/10;
  const int t = threadIdx.x;
  const float* xb = X1f + (size_t)b*NPTS*64;

  if (t < 80){
    const int n = n0 + t;
    idxC[t] = IDX[((size_t)b*NPTS + n/10)*KNB + (n%10)];
  }
  __syncthreads();

  const int tmv = t>>4, tnv = t&15, tnv5 = tnv*5;
  const int p_loc = tnv>>1, jh5 = (tnv&1)*5;
  const int o = t&127, phalf = t>>7;
  const float rs = 1.f/sqrtf(1.f + 1e-5f);
  float acc2[4] = {};

  for (int ch=0; ch<2; ch++){
    for (int i=t; i<4096; i+=256){
      const int k = i&63, cl = i>>6;
      smC[C_WC2T + k*68 + cl] = wc2[(size_t)(ch*64+cl)*64 + k];
      smC[C_XCDT + k*68 + cl] = xc[(size_t)(ch*64+cl)*128 + 64 + k];
    }
    for (int i=t; i<5120; i+=256){
      const int n = i%80, k = i/80;
      smC[C_W1S + k*82 + n] = W1[((size_t)(b-bbase)*64 + k)*NT + n0 + n];
    }
    {
      const float4* xb4 = (const float4*)xb;
      #pragma unroll
      for (int r=0;r<5;r++){
        const int i = t + r*256;
        const int pos = i>>4, q4 = i&15;
        const float4 v = xb4[(size_t)idxC[pos]*16 + q4];
        smC[C_NBRS + (q4*4+0)*82 + pos] = v.x;
        smC[C_NBRS + (q4*4+1)*82 + pos] = v.y;
        smC[C_NBRS + (q4*4+2)*82 + pos] = v.z;
        smC[C_NBRS + (q4*4+3)*82 + pos] = v.w;
      }
    }
    __syncthreads();

    float accw[4][5] = {}, acch[4][5] = {};
    #pragma unroll 2
    for (int k=0;k<64;k++){
      float4 a4 = *(const float4*)&smC[C_WC2T + k*68 + tmv*4];
      float4 x4 = *(const float4*)&smC[C_XCDT + k*68 + tmv*4];
      const float av[4] = {a4.x,a4.y,a4.z,a4.w};
      const float xv[4] = {x4.x,x4.y,x4.z,x4.w};
      float bw[5], bh[5];
      #pragma unroll
      for (int j=0;j<5;j++){
        bw[j] = smC[C_W1S  + k*82 + tnv5 + j];
        bh[j] = smC[C_NBRS + k*82 + tnv5 + j];
      }
      #pragma unroll
      for (int i2=0;i2<4;i2++)
        #pragma unroll
        for (int j=0;j<5;j++){ accw[i2][j]+=av[i2]*bw[j]; acch[i2][j]+=xv[i2]*bh[j]; }
    }

    float hwreg[4][5];
    #pragma unroll
    for (int i2=0;i2<4;i2++){
      const int c = ch*64 + tmv*4 + i2;
      const float s2 = bn2g[c]*rs, b2 = bn2b[c], cb2 = wcb2[c];
      const float sx = xbng[c]*rs, bx = xbnb[c], cbx = xcb[c];
      const float hcc = HCC[((size_t)b*128 + c)*NPTS + p0 + p_loc];
      float w2[5], hv[5];
      #pragma unroll
      for (int j=0;j<5;j++){
        w2[j] = lrelu((accw[i2][j] + cb2)*s2 + b2, 0.01f);
        hv[j] = lrelu((acch[i2][j] + hcc + cbx)*sx + bx, 0.01f);
      }
      float mx = w2[0];
      #pragma unroll
      for (int j=1;j<5;j++) mx = fmaxf(mx, w2[j]);
      mx = fmaxf(mx, __shfl_xor(mx, 1));
      float ssum = 0.f;
      #pragma unroll
      for (int j=0;j<5;j++){ w2[j] = expf(w2[j]-mx); ssum += w2[j]; }
      ssum += __shfl_xor(ssum, 1);
      const float inv = 1.f/ssum;
      #pragma unroll
      for (int j=0;j<5;j++) hwreg[i2][j] = hv[j]*(w2[j]*inv);
    }
    __syncthreads();

    #pragma unroll
    for (int i2=0;i2<4;i2++){
      const int cl = tmv*4 + i2;
      #pragma unroll
      for (int j=0;j<5;j++)
        smC[C_HW + p_loc*648 + cl*10 + jh5 + j] = hwreg[i2][j];
    }
    __syncthreads();

    for (int kc=0; kc<640; kc+=64){
      #pragma unroll
      for (int r=0;r<32;r++){
        const int i = t + r*256;
        const int oo = i>>6, kk = i&63;
        smC[C_OWL + oo*65 + kk] = oW[(size_t)oo*1280 + ch*640 + kc + kk];
      }
      __syncthreads();
      #pragma unroll 4
      for (int kk=0; kk<64; kk+=4){
        const float w0 = smC[C_OWL + o*65 + kk];
        const float w1v= smC[C_OWL + o*65 + kk+1];
        const float w2v= smC[C_OWL + o*65 + kk+2];
        const float w3v= smC[C_OWL + o*65 + kk+3];
        #pragma unroll
        for (int pp=0;pp<4;pp++){
          const float4 h4 = *(const float4*)&smC[C_HW + (phalf*4+pp)*648 + kc + kk];
          acc2[pp] += w0*h4.x + w1v*h4.y + w2v*h4.z + w3v*h4.w;
        }
      }
      __syncthreads();
    }
  }
  const float obv = ob[o];
  #pragma unroll
  for (int pp=0;pp<4;pp++)
    X2[((size_t)b*128 + o)*NPTS + p0 + phalf*4 + pp] = acc2[pp] + obv;
}

// ---------------------------------------------------------------------------
template<int CH>
__global__ __launch_bounds__(256) void adain_kernel(
    float* __restrict__ X, const float* __restrict__ S)
{
  const int c = blockIdx.x, b = blockIdx.y;
  const int t = threadIdx.x;
  const size_t base = ((size_t)b*CH + c)*NPTS;
  __shared__ float red[256];
  float v[8];
  float s = 0.f;
  #pragma unroll
  for (int i=0;i<8;i++){
    float xv = X[base + t + i*256];
    xv = lrelu(xv, 0.2f);
    v[i] = xv; s += xv;
  }
  red[t] = s; __syncthreads();
  for (int st=128; st>0; st>>=1){ if (t<st) red[t] += red[t+st]; __syncthreads(); }
  const float mean = red[0]*(1.f/NPTS);
  __syncthreads();
  float s2 = 0.f;
  #pragma unroll
  for (int i=0;i<8;i++){ const float d = v[i]-mean; s2 += d*d; }
  red[t] = s2; __syncthreads();
  for (int st=128; st>0; st>>=1){ if (t<st) red[t] += red[t+st]; __syncthreads(); }
  const float var  = red[0]*(1.f/NPTS);
  const float rstd = 1.f/sqrtf(var + 1e-5f);
  const float* g  = S + ((size_t)b*2*CH + c)*NPTS;
  const float* be = S + ((size_t)b*2*CH + CH + c)*NPTS;
  #pragma unroll
  for (int i=0;i<8;i++){
    const int n = t + i*256;
    X[base+n] = g[n]*((v[i]-mean)*rstd) + be[n];
  }
}

__global__ __launch_bounds__(256) void maxn_kernel(const float* __restrict__ X, float* __restrict__ FG)
{
  const int c = blockIdx.x, b = blockIdx.y;
  const int t = threadIdx.x;
  const float* p = X + ((size_t)b*128 + c)*NPTS;
  __shared__ float red[256];
  float m = -3.4e38f;
  for (int i=t; i<NPTS; i+=256) m = fmaxf(m, p[i]);
  red[t] = m; __syncthreads();
  for (int st=128; st>0; st>>=1){ if (t<st) red[t] = fmaxf(red[t], red[t+st]); __syncthreads(); }
  if (t == 0) FG[b*128+c] = red[0];
}

__global__ __launch_bounds__(512) void fc_kernel(
    const float* __restrict__ FG,
    const float* __restrict__ gW1, const float* __restrict__ gb1,
    const float* __restrict__ gbn1g, const float* __restrict__ gbn1b,
    const float* __restrict__ gW2, const float* __restrict__ gb2,
    const float* __restrict__ gbn2g, const float* __restrict__ gbn2b,
    const float* __restrict__ tW1, const float* __restrict__ tb1,
    float* __restrict__ FGP)
{
  const int b = blockIdx.x, t = threadIdx.x;
  __shared__ float fg[128], h1[128], h2[512];
  const float rs = 1.f/sqrtf(1.f + 1e-5f);
  if (t < 128) fg[t] = FG[b*128+t];
  __syncthreads();
  if (t < 128){
    float s = 0.f;
    for (int c=0;c<128;c++) s += gW1[t*128+c]*fg[c];
    s += gb1[t];
    s = s*(gbn1g[t]*rs) + gbn1b[t];
    h1[t] = lrelu(s, 0.01f);
  }
  __syncthreads();
  {
    float s = 0.f;
    for (int c=0;c<128;c++) s += gW2[t*128+c]*h1[c];
    s += gb2[t];
    s = s*(gbn2g[t]*rs) + gbn2b[t];
    h2[t] = lrelu(s, 0.01f);
  }
  __syncthreads();
  if (t < 256){
    float s = tb1[t];
    for (int c=0;c<512;c++) s += tW1[(size_t)t*640 + c]*h2[c];
    FGP[b*256+t] = s;
  }
}

__global__ __launch_bounds__(256) void t3_kernel(
    const float* __restrict__ T2, const float* __restrict__ tW3,
    const float* __restrict__ tb3, float* __restrict__ outp)
{
  __shared__ float w[192];
  const int t = threadIdx.x;
  if (t < 192) w[t] = tW3[t];
  __syncthreads();
  const int b = blockIdx.y;
  const int n = blockIdx.x*256 + t;
  float a0 = tb3[0], a1 = tb3[1], a2 = tb3[2];
  for (int c=0;c<64;c++){
    const float v = T2[((size_t)b*64+c)*NPTS + n];
    a0 += w[c]*v; a1 += w[64+c]*v; a2 += w[128+c]*v;
  }
  float* op = outp + ((size_t)b*NPTS + n)*3;
  op[0]=a0; op[1]=a1; op[2]=a2;
}

// ---------------------------------------------------------------------------
extern "C" void kernel_launch(void* const* d_in, const int* in_sizes, int n_in,
                              void* d_out, int out_size, void* d_ws, size_t ws_size,
                              hipStream_t stream)
{
  (void)in_sizes; (void)n_in; (void)out_size; (void)ws_size;
  const float* z    = (const float*)d_in[0];
  const float* x    = (const float*)d_in[1];
  const float* hW1  = (const float*)d_in[2];
  const float* hb1  = (const float*)d_in[3];
  const float* hW2  = (const float*)d_in[4];
  const float* hb2  = (const float*)d_in[5];
  const float* e1_wc1 = (const float*)d_in[6];
  const float* e1_wcb1= (const float*)d_in[7];
  const float* e1_bn1g= (const float*)d_in[8];
  const float* e1_bn1b= (const float*)d_in[9];
  const float* e1_wc2 = (const float*)d_in[10];
  const float* e1_wcb2= (const float*)d_in[11];
  const float* e1_bn2g= (const float*)d_in[12];
  const float* e1_bn2b= (const float*)d_in[13];
  const float* e1_xc  = (const float*)d_in[14];
  const float* e1_xcb = (const float*)d_in[15];
  const float* e1_xbng= (const float*)d_in[16];
  const float* e1_xbnb= (const float*)d_in[17];
  const float* e1_oW  = (const float*)d_in[18];
  const float* e1_ob  = (const float*)d_in[19];
  const float* a1_W   = (const float*)d_in[20];
  const float* a1_b   = (const float*)d_in[21];
  const float* e2_wc1 = (const float*)d_in[22];
  const float* e2_wcb1= (const float*)d_in[23];
  const float* e2_bn1g= (const float*)d_in[24];
  const float* e2_bn1b= (const float*)d_in[25];
  const float* e2_wc2 = (const float*)d_in[26];
  const float* e2_wcb2= (const float*)d_in[27];
  const float* e2_bn2g= (const float*)d_in[28];
  const float* e2_bn2b= (const float*)d_in[29];
  const float* e2_xc  = (const float*)d_in[30];
  const float* e2_xcb = (const float*)d_in[31];
  const float* e2_xbng= (const float*)d_in[32];
  const float* e2_xbnb= (const float*)d_in[33];
  const float* e2_oW  = (const float*)d_in[34];
  const float* e2_ob  = (const float*)d_in[35];
  const float* a2_W   = (const float*)d_in[36];
  const float* a2_b   = (const float*)d_in[37];
  const float* gW1    = (const float*)d_in[38];
  const float* gb1    = (const float*)d_in[39];
  const float* gbn1g  = (const float*)d_in[40];
  const float* gbn1b  = (const float*)d_in[41];
  const float* gW2    = (const float*)d_in[42];
  const float* gb2    = (const float*)d_in[43];
  const float* gbn2g  = (const float*)d_in[44];
  const float* gbn2b  = (const float*)d_in[45];
  const float* tW1    = (const float*)d_in[46];
  const float* tb1    = (const float*)d_in[47];
  const float* tW2    = (const float*)d_in[48];
  const float* tb2    = (const float*)d_in[49];
  const float* tW3    = (const float*)d_in[50];
  const float* tb3    = (const float*)d_in[51];
  float* out = (float*)d_out;
  float* ws  = (float*)d_ws;

  // workspace layout (float units) — total ~18.6M floats ≈ 74.4 MB
  size_t off = 0;
  float*  ST    = ws + off; off += (size_t)BATCH*128*NPTS;    // 2,097,152
  float*  Sbuf  = ws + off; off += (size_t)BATCH*256*NPTS;    // 4,194,304
  float*  X1f   = ws + off; off += (size_t)BATCH*NPTS*64;     // 1,048,576
  float*  X2    = ws + off; off += (size_t)BATCH*128*NPTS;    // 2,097,152
  float*  T1    = ws + off; off += (size_t)BATCH*256*NPTS;    // 4,194,304
  float*  T2    = ws + off; off += (size_t)BATCH*64*NPTS;     //   524,288
  int*    IDX   = (int*)(ws + off); off += (size_t)BATCH*NPTS*KNB;  // 163,840
  float*  OW1T  = ws + off; off += (size_t)64*64*KNB;         //  40,960
  float*  XN3f  = ws + off; off += (size_t)BATCH*NPTS;        //  16,384
  double* XN64  = (double*)(ws + off); off += (size_t)2*BATCH*NPTS; // 32,768
  float*  FG    = ws + off; off += (size_t)BATCH*128;
  float*  FGP   = ws + off; off += (size_t)BATCH*256;
  off = (off + 1) & ~(size_t)1;
  double* X1_64 = (double*)(ws + off); off += (size_t)2*BATCH*64*NPTS;  // 2,097,152 fl
  double* X1T64 = (double*)(ws + off); off += (size_t)2*BATCH*NPTS*64;  // 2,097,152 fl

  // aliases (time-disjoint; liveness table):
  //  - TOPD/TOPI: live only between knn_part3 and knn_merge
  //  - TOPF: (float*)X1_64, 16384*8*16 = 2,097,152 fl exact fit; X1_64 dead
  //          after transpose_cast64 (refine reads X1T64)
  //  - TOPI2: (int*)T1; T1 dead between style head and kernelA
  //  - X1c = Sbuf[0:1M]: written by transpose_cast64, read by kernelP —
  //          never clobbered in between (R10 lesson)
  double* TOPD  = (double*)T1;
  int*    TOPI  = (int*)Sbuf;
  float*  TOPF  = (float*)X1_64;
  int*    TOPI2 = (int*)T1;
  float*  X1c   = Sbuf;                 // (B,64,N) f32 chan-major
  float*  WCC   = Sbuf + 1048576;       // (B,64,N)
  float*  HCC   = Sbuf + 2097152;       // (B,128,N)
  float*  W1    = T1;                   // 2 batches x [64][NT] (after refine)

  // oW transpose for edge1
  owt_kernel<64><<<(64*64*KNB+255)/256, 256, 0, stream>>>(e1_oW, OW1T);

  // style head (np-exact f32)
  head1_exact<<<dim3(32,2,8), 256, 0, stream>>>(x, z, hW1, hb1, T1);
  gemm_bn<128,128,true><<<dim3(NPTS/128,1,8), 256, 0, stream>>>(
      T1, NPTS, (size_t)128*NPTS, 0, hW2, 128, 0, hb2, nullptr, nullptr, nullptr, 0,
      ST, NPTS, (size_t)128*NPTS, 128, 1, 0.01f, 0);

  // edge block 1
  norms3_f32<<<64, 256, 0, stream>>>(x, XN3f);
  knn_part3<<<512, 256, 0, stream>>>(x, XN3f, TOPD, TOPI);
  knn_merge_kernel<<<64, 256, 0, stream>>>(TOPD, TOPI, IDX);
  edge1_f64<<<2048, 512, 0, stream>>>(
      x, IDX, e1_wc1, e1_wcb1, e1_bn1g, e1_bn1b, e1_wc2, e1_wcb2, e1_bn2g, e1_bn2b,
      e1_xc, e1_xcb, e1_xbng, e1_xbnb, OW1T, e1_ob, X1_64);
  gemm_bn<128,128,true><<<dim3(NPTS/128,1,8), 256, 0, stream>>>(
      ST, NPTS, (size_t)128*NPTS, 0, a1_W, 128, 0, a1_b, nullptr, nullptr, nullptr, 0,
      Sbuf, NPTS, (size_t)128*NPTS, 128, 0, 0.f, 0);
  adain1_f64<<<dim3(64,8), 256, 0, stream>>>(X1_64, Sbuf);

  // x1 -> n-major f64 + f32, chan-major f32
  transpose_cast64<<<dim3(32,8), 256, 0, stream>>>(X1_64, X1T64, X1f, X1c);

  // block2 kNN: f32 coarse (LDS-tiled) + f64 refine
  norms64_f32<<<64, 256, 0, stream>>>(X1f, XN3f);
  norms64d<<<64, 256, 0, stream>>>(X1T64, XN64);
  knn_coarse<<<512, 256, 0, stream>>>(X1f, XN3f, TOPF, TOPI2);
  knn_refine<<<64, 256, 0, stream>>>(TOPF, TOPI2, X1T64, XN64, IDX);

  // edge block 2 pipeline
  kernelP<<<dim3(16,3,8), 256, 0, stream>>>(X1c, e2_wc1, e2_xc, WCC, HCC);
  for (int lb=0; lb<4; lb++){
    const int bbase = lb*2;
    kernelA<<<dim3(NT/128,1,2), 256, 0, stream>>>(
        X1f, IDX, WCC, e2_wc1, e2_wcb1, e2_bn1g, e2_bn1b, W1, bbase);
    kernelC<<<dim3(NT/80,1,2), 256, 0, stream>>>(
        X1f, IDX, W1, HCC, e2_wc2, e2_wcb2, e2_bn2g, e2_bn2b,
        e2_xc, e2_xcb, e2_xbng, e2_xbnb, e2_oW, e2_ob, X2, bbase);
  }

  // adain2
  gemm_bn<128,128><<<dim3(NPTS/128,2,8), 256, 0, stream>>>(
      ST, NPTS, (size_t)128*NPTS, 0, a2_W, 128, 0, a2_b, nullptr, nullptr, nullptr, 0,
      Sbuf, NPTS, (size_t)256*NPTS, 128, 0, 0.f, 0);
  adain_kernel<128><<<dim3(128,8), 256, 0, stream>>>(X2, Sbuf);

  // global feature + final MLP
  maxn_kernel<<<dim3(128,8), 256, 0, stream>>>(X2, FG);
  fc_kernel<<<8, 512, 0, stream>>>(FG, gW1, gb1, gbn1g, gbn1b, gW2, gb2, gbn2g, gbn2b, tW1, tb1, FGP);
  gemm_bn<128,128><<<dim3(NPTS/128,2,8), 256, 0, stream>>>(
      X2, NPTS, (size_t)128*NPTS, 0, tW1, 640, 512, nullptr, nullptr, nullptr, FGP, 256,
      T1, NPTS, (size_t)256*NPTS, 128, 1, 0.01f, 0);
  gemm_bn<64,128><<<dim3(NPTS/128,1,8), 256, 0, stream>>>(
      T1, NPTS, (size_t)256*NPTS, 0, tW2, 256, 0, tb2, nullptr, nullptr, nullptr, 0,
      T2, NPTS, (size_t)64*NPTS, 256, 1, 0.01f, 0);
  t3_kernel<<<dim3(8,8), 256, 0, stream>>>(T2, tW3, tb3, out);
}

// Round 13
// 1551.696 us; speedup vs baseline: 1.0142x; 1.0045x over previous
//
#include <hip/hip_runtime.h>
#include <math.h>

#define NPTS 2048
#define BATCH 8
#define KNB 10
#define NT (NPTS*KNB)   // 20480 positions per batch (point*10+j)

static __device__ __forceinline__ float lrelu(float x, float s){ return x >= 0.f ? x : s*x; }
static __device__ __forceinline__ double lrelu_d(double x, double s){ return x >= 0.0 ? x : s*x; }

// ---------------------------------------------------------------------------
// Tiled GEMM with fused epilogue. EXACT=true bit-matches numpy einsum
// 'bcn,oc->bon' (+bias, opt lrelu): single f32 acc, ascending k, no FMA.
// ---------------------------------------------------------------------------
template<int TM, int TN, bool EXACT=false>
__global__ __launch_bounds__(256) void gemm_bn(
    const float* __restrict__ In, int ldn, size_t inBS, int koff,
    const float* __restrict__ W, int wstride, int wcol0,
    const float* __restrict__ cb, const float* __restrict__ bng, const float* __restrict__ bnb,
    const float* __restrict__ addBO, int addM,
    float* __restrict__ Out, int ldo, size_t outBS,
    int C, int act, float neg, int bbase)
{
  constexpr int RM = TM/16, RN = TN/16;
  __shared__ float As[16][TM+4];
  __shared__ float Bs[16][TN+4];
  const int b = bbase + blockIdx.z;
  const float* in = In + (size_t)b*inBS;
  float* outp = Out + (size_t)b*outBS;
  const int m0 = blockIdx.y*TM, n0 = blockIdx.x*TN;
  const int t = threadIdx.x;
  const int tmv = t>>4, tnv = t&15;
  float acc[RM][RN] = {};
  for (int k0=0; k0<C; k0+=16){
    #pragma unroll
    for (int s=0;s<RM;s++){
      const int i = t + s*256;
      const int k = i&15, m = i>>4;
      As[k][m] = W[(size_t)(m0+m)*wstride + wcol0 + k0 + k];
    }
    #pragma unroll
    for (int s=0;s<RN;s++){
      const int i = t + s*256;
      const int n = i & (TN-1), kk2 = i / TN;
      Bs[kk2][n] = in[(size_t)(koff + k0 + kk2)*ldn + n0 + n];
    }
    __syncthreads();
    #pragma unroll
    for (int kk=0;kk<16;kk++){
      float av[RM], bv[RN];
      #pragma unroll
      for (int s=0;s<RM/4;s++){
        float4 v = *(const float4*)&As[kk][tmv*RM + s*4];
        av[s*4]=v.x; av[s*4+1]=v.y; av[s*4+2]=v.z; av[s*4+3]=v.w;
      }
      #pragma unroll
      for (int s=0;s<RN/4;s++){
        float4 v = *(const float4*)&Bs[kk][tnv*RN + s*4];
        bv[s*4]=v.x; bv[s*4+1]=v.y; bv[s*4+2]=v.z; bv[s*4+3]=v.w;
      }
      #pragma unroll
      for (int i2=0;i2<RM;i2++)
        #pragma unroll
        for (int j2=0;j2<RN;j2++){
          if constexpr (EXACT)
            acc[i2][j2] = __fadd_rn(acc[i2][j2], __fmul_rn(av[i2], bv[j2]));
          else
            acc[i2][j2] += av[i2]*bv[j2];
        }
    }
    __syncthreads();
  }
  const float rs = 1.f/sqrtf(1.f + 1e-5f);
  #pragma unroll
  for (int i2=0;i2<RM;i2++){
    const int gm = m0 + tmv*RM + i2;
    float addv = cb ? cb[gm] : 0.f;
    if (addBO) addv += addBO[b*addM + gm];
    float sc = 1.f, bs = 0.f;
    if (bng){ sc = bng[gm]*rs; bs = bnb[gm]; }
    float* orow = outp + (size_t)gm*ldo + n0 + tnv*RN;
    #pragma unroll
    for (int j4=0;j4<RN/4;j4++){
      float4 o;
      float vv[4];
      #pragma unroll
      for (int q=0;q<4;q++){
        float v;
        if constexpr (EXACT){
          v = __fadd_rn(acc[i2][j4*4+q], addv);
          if (act) v = (v >= 0.f) ? v : __fmul_rn(neg, v);
        } else {
          v = acc[i2][j4*4+q] + addv;
          if (bng) v = v*sc + bs;
          if (act) v = lrelu(v, neg);
        }
        vv[q] = v;
      }
      o.x=vv[0]; o.y=vv[1]; o.z=vv[2]; o.w=vv[3];
      *(float4*)&orow[j4*4] = o;
    }
  }
}

// ---------------------------------------------------------------------------
// Head layer 1 (EXACT): C=131 gathered from x (B,N,3), z (B,N,128); lrelu 0.01
// ---------------------------------------------------------------------------
__global__ __launch_bounds__(256) void head1_exact(
    const float* __restrict__ x, const float* __restrict__ z,
    const float* __restrict__ W, const float* __restrict__ bias,
    float* __restrict__ outh)
{
  __shared__ float As[16][68];
  __shared__ float Bs[16][68];
  const int b = blockIdx.z;
  const int m0 = blockIdx.y*64, n0 = blockIdx.x*64;
  const int t = threadIdx.x;
  const int tm = t>>4, tn = t&15;
  float acc[4][4] = {};
  for (int k0 = 0; k0 < 144; k0 += 16){
    #pragma unroll
    for (int i=0;i<4;i++){
      const int ii = t + i*256;
      const int k = ii&15, m = ii>>4;
      const int gk = k0+k;
      As[k][m] = (gk<131) ? W[(size_t)(m0+m)*131 + gk] : 0.f;
    }
    #pragma unroll
    for (int i=0;i<4;i++){
      const int ii = t + i*256;
      const int k = ii&15, nn = ii>>4;
      const int gk = k0+k, gn = n0+nn;
      float v = 0.f;
      if (gk < 3)        v = x[((size_t)b*NPTS+gn)*3   + gk];
      else if (gk < 131) v = z[((size_t)b*NPTS+gn)*128 + (gk-3)];
      Bs[k][nn] = v;
    }
    __syncthreads();
    #pragma unroll
    for (int k=0;k<16;k++){
      #pragma unroll
      for (int i=0;i<4;i++){
        const float a = As[k][tm*4+i];
        #pragma unroll
        for (int j=0;j<4;j++){
          acc[i][j] = __fadd_rn(acc[i][j], __fmul_rn(a, Bs[k][tn*4+j]));
        }
      }
    }
    __syncthreads();
  }
  #pragma unroll
  for (int i=0;i<4;i++){
    const int gm = m0 + tm*4 + i;
    #pragma unroll
    for (int j=0;j<4;j++){
      float v = __fadd_rn(acc[i][j], bias[gm]);
      v = (v >= 0.f) ? v : __fmul_rn(0.01f, v);
      outh[((size_t)b*128+gm)*NPTS + n0 + tn*4 + j] = v;
    }
  }
}

// ---------------------------------------------------------------------------
// Block-1 kNN: f32 np-exact.
// ---------------------------------------------------------------------------
__global__ __launch_bounds__(256) void norms3_f32(const float* __restrict__ Xn, float* __restrict__ XN)
{
  const int q = blockIdx.x*256 + threadIdx.x;
  const float* p = Xn + (size_t)q*3;
  float s = __fmul_rn(p[0],p[0]);
  s = __fadd_rn(s, __fmul_rn(p[1],p[1]));
  s = __fadd_rn(s, __fmul_rn(p[2],p[2]));
  XN[q] = s;
}

__global__ __launch_bounds__(256) void knn_part3(
    const float* __restrict__ Xn, const float* __restrict__ XN,
    double* __restrict__ topd, int* __restrict__ topi)
{
  const int t = threadIdx.x;
  const int qloc = t & 31, part = t >> 5;
  const int q = blockIdx.x*32 + qloc;
  const int b = q >> 11, n = q & (NPTS-1);
  const float* xb = Xn + (size_t)b*NPTS*3;
  const float qx = xb[(size_t)n*3+0], qy = xb[(size_t)n*3+1], qz = xb[(size_t)n*3+2];
  const float qn = XN[q];
  float td[11]; int ti[11];
  #pragma unroll
  for (int r=0;r<11;r++){ td[r] = 3.4e38f; ti[r] = 0x7fffffff; }
  const int m0 = part*(NPTS/8);
  for (int mm=0; mm<NPTS/8; mm++){
    const int m = m0 + mm;
    float dot = __fmul_rn(qx, xb[(size_t)m*3+0]);
    dot = __fadd_rn(dot, __fmul_rn(qy, xb[(size_t)m*3+1]));
    dot = __fadd_rn(dot, __fmul_rn(qz, xb[(size_t)m*3+2]));
    float dist = __fmul_rn(-2.f, dot);
    dist = __fadd_rn(dist, qn);
    dist = __fadd_rn(dist, XN[b*NPTS + m]);
    if (dist < td[10]){
      td[10] = dist; ti[10] = m;
      #pragma unroll
      for (int p=10;p>0;p--){
        if (td[p] < td[p-1]){
          float tf=td[p]; td[p]=td[p-1]; td[p-1]=tf;
          int   tt=ti[p]; ti[p]=ti[p-1]; ti[p-1]=tt;
        }
      }
    }
  }
  const size_t base = ((size_t)q*8 + part)*11;
  #pragma unroll
  for (int r=0;r<11;r++){ topd[base+r] = (double)td[r]; topi[base+r] = ti[r]; }
}

__global__ __launch_bounds__(256) void knn_merge_kernel(
    const double* __restrict__ topd, const int* __restrict__ topi, int* __restrict__ idxout)
{
  const int q = blockIdx.x*256 + threadIdx.x;
  double td[11]; int ti[11];
  #pragma unroll
  for (int r=0;r<11;r++){ td[r] = 1.0e308; ti[r] = 0x7fffffff; }
  const size_t base = (size_t)q*88;
  for (int s=0; s<88; s++){
    const double d = topd[base+s];
    const int  im = topi[base+s];
    if (d < td[10] || (d == td[10] && im < ti[10])){
      td[10] = d; ti[10] = im;
      #pragma unroll
      for (int p=10;p>0;p--){
        const bool sw = (td[p] < td[p-1]) || (td[p] == td[p-1] && ti[p] < ti[p-1]);
        if (sw){
          double tf=td[p]; td[p]=td[p-1]; td[p-1]=tf;
          int    tt=ti[p]; ti[p]=ti[p-1]; ti[p-1]=tt;
        }
      }
    }
  }
  #pragma unroll
  for (int j=0;j<KNB;j++) idxout[(size_t)q*KNB + j] = ti[j+1];
}

// ---------------------------------------------------------------------------
// Block-2 kNN stage 1: LDS-tiled candidates + in-register top-16 (R9 proven).
// ---------------------------------------------------------------------------
__global__ __launch_bounds__(256) void norms64_f32(const float* __restrict__ Xn, float* __restrict__ XN)
{
  const int q = blockIdx.x*256 + threadIdx.x;
  const float4* p4 = (const float4*)(Xn + (size_t)q*64);
  float s0=0.f,s1=0.f,s2=0.f,s3=0.f;
  #pragma unroll
  for (int d4=0; d4<16; d4++){
    float4 v = p4[d4];
    s0 += v.x*v.x; s1 += v.y*v.y; s2 += v.z*v.z; s3 += v.w*v.w;
  }
  XN[q] = (s0+s1)+(s2+s3);
}

__global__ __launch_bounds__(256) void knn_coarse(
    const float* __restrict__ Xn, const float* __restrict__ XN,
    float* __restrict__ topf, int* __restrict__ topi)
{
  __shared__ float Cs[64][68];
  __shared__ float xns[64];
  const int t = threadIdx.x;
  const int tq = t>>3, p = t&7;
  const int q0 = blockIdx.x*32;
  const int b  = q0 >> 11;
  const int gq = q0 + tq;
  const int nloc = (q0 & (NPTS-1)) + tq;
  const float* xb = Xn + (size_t)b*NPTS*64;
  float qv[64];
  {
    const float4* p4 = (const float4*)(xb + (size_t)nloc*64);
    #pragma unroll
    for (int d4=0; d4<16; d4++){ float4 v = p4[d4]; qv[d4*4]=v.x; qv[d4*4+1]=v.y; qv[d4*4+2]=v.z; qv[d4*4+3]=v.w; }
  }
  const float qn = XN[gq];
  float td[16]; int ti[16];
  #pragma unroll
  for (int r=0;r<16;r++){ td[r] = 3.4e38f; ti[r] = 0x7fffffff; }

  for (int m0=0; m0<NPTS; m0+=64){
    __syncthreads();
    #pragma unroll
    for (int s=0;s<4;s++){
      const int i = t + s*256;
      const int row = i>>4, f4 = i&15;
      float4 v = *(const float4*)(xb + (size_t)(m0+row)*64 + f4*4);
      *(float4*)&Cs[row][f4*4] = v;
    }
    if (t < 64) xns[t] = XN[b*NPTS + m0 + t];
    __syncthreads();
    #pragma unroll
    for (int jj=0;jj<8;jj++){
      const int row = jj*8 + p;
      float d0=0.f,d1=0.f,d2=0.f,d3=0.f;
      #pragma unroll
      for (int k4=0;k4<16;k4++){
        float4 v = *(const float4*)&Cs[row][k4*4];
        d0 += qv[k4*4+0]*v.x; d1 += qv[k4*4+1]*v.y;
        d2 += qv[k4*4+2]*v.z; d3 += qv[k4*4+3]*v.w;
      }
      const float dist = qn - 2.f*((d0+d1)+(d2+d3)) + xns[row];
      const int m = m0 + row;
      if (dist < td[15]){
        td[15] = dist; ti[15] = m;
        #pragma unroll
        for (int pp=15;pp>0;pp--){
          if (td[pp] < td[pp-1]){
            float tf=td[pp]; td[pp]=td[pp-1]; td[pp-1]=tf;
            int   tt=ti[pp]; ti[pp]=ti[pp-1]; ti[pp-1]=tt;
          }
        }
      }
    }
  }
  const size_t base = ((size_t)gq*8 + p)*16;
  #pragma unroll
  for (int r=0;r<16;r++){ topf[base+r] = td[r]; topi[base+r] = ti[r]; }
}

// ---------------------------------------------------------------------------
// Block-2 kNN stage 2: merge 8x16 -> f32 top-16, f64 re-rank, emit 10.
// ---------------------------------------------------------------------------
__global__ __launch_bounds__(256) void norms64d(const double* __restrict__ Xn, double* __restrict__ XN)
{
  const int q = blockIdx.x*256 + threadIdx.x;
  const double* p = Xn + (size_t)q*64;
  double s = 0.0;
  #pragma unroll
  for (int d=0; d<64; d++) s += p[d]*p[d];
  XN[q] = s;
}

__global__ __launch_bounds__(256) void knn_refine(
    const float* __restrict__ topf, const int* __restrict__ topi,
    const double* __restrict__ Xd, const double* __restrict__ XNd,
    int* __restrict__ idxout)
{
  const int q = blockIdx.x*256 + threadIdx.x;
  const int b = q >> 11;
  float tf[16]; int ti[16];
  #pragma unroll
  for (int r=0;r<16;r++){ tf[r] = 3.4e38f; ti[r] = 0x7fffffff; }
  const size_t base = (size_t)q*128;
  for (int s=0; s<128; s++){
    const float d = topf[base+s];
    const int  im = topi[base+s];
    if (d < tf[15] || (d == tf[15] && im < ti[15])){
      tf[15] = d; ti[15] = im;
      #pragma unroll
      for (int p=15;p>0;p--){
        const bool sw = (tf[p] < tf[p-1]) || (tf[p] == tf[p-1] && ti[p] < ti[p-1]);
        if (sw){
          float a=tf[p]; tf[p]=tf[p-1]; tf[p-1]=a;
          int   c=ti[p]; ti[p]=ti[p-1]; ti[p-1]=c;
        }
      }
    }
  }
  double qv[64];
  {
    const double2* p2 = (const double2*)(Xd + (size_t)q*64);
    #pragma unroll
    for (int d2=0; d2<32; d2++){ double2 v = p2[d2]; qv[d2*2]=v.x; qv[d2*2+1]=v.y; }
  }
  const double qn = XNd[q];
  double dd[11]; int di[11];
  #pragma unroll
  for (int r=0;r<11;r++){ dd[r] = 1.0e308; di[r] = 0x7fffffff; }
  for (int s=0; s<16; s++){
    const int m = ti[s];
    const double2* c2 = (const double2*)(Xd + ((size_t)(b*NPTS + m))*64);
    double d0=0.0,d1=0.0,d2s=0.0,d3=0.0;
    #pragma unroll
    for (int d4=0; d4<16; d4++){
      double2 va = c2[d4*2], vb = c2[d4*2+1];
      d0 += qv[d4*4+0]*va.x; d1 += qv[d4*4+1]*va.y;
      d2s+= qv[d4*4+2]*vb.x; d3 += qv[d4*4+3]*vb.y;
    }
    const double dot = (d0+d1)+(d2s+d3);
    const double dist = (qn - 2.0*dot) + XNd[b*NPTS + m];
    if (dist < dd[10] || (dist == dd[10] && m < di[10])){
      dd[10] = dist; di[10] = m;
      #pragma unroll
      for (int p=10;p>0;p--){
        const bool sw = (dd[p] < dd[p-1]) || (dd[p] == dd[p-1] && di[p] < di[p-1]);
        if (sw){
          double a=dd[p]; dd[p]=dd[p-1]; dd[p-1]=a;
          int    c=di[p]; di[p]=di[p-1]; di[p-1]=c;
        }
      }
    }
  }
  #pragma unroll
  for (int j=0;j<KNB;j++) idxout[(size_t)q*KNB + j] = di[j+1];
}

// ---------------------------------------------------------------------------
// Edge block 1 (mixed precision, np-matched) — register-ized; phase-2 einsum
// reads oWT DIRECTLY from global (coalesced, L2-hot) instead of LDS staging:
// removes 20 __syncthreads + 10 staging sweeps per block. Same value stream
// and accumulate order -> bit-identical output.
// ---------------------------------------------------------------------------
__global__ __launch_bounds__(512) void edge1_f64(
    const float* __restrict__ Xn, const int* __restrict__ idx,
    const float* __restrict__ wc1, const float* __restrict__ wcb1,
    const float* __restrict__ bn1g, const float* __restrict__ bn1b,
    const float* __restrict__ wc2, const float* __restrict__ wcb2,
    const float* __restrict__ bn2g, const float* __restrict__ bn2b,
    const float* __restrict__ xc,  const float* __restrict__ xcb,
    const float* __restrict__ xbng, const float* __restrict__ xbnb,
    const float* __restrict__ oWT, const float* __restrict__ ob,
    double* __restrict__ outX)
{
  __shared__ double w1bd[8][32];
  __shared__ double hwbd[8][64];

  const int t = threadIdx.x;
  const int wid = t>>6, lane = t&63;
  const double sq = sqrt(1.0 + 1e-5);
  const int m31 = lane & 31;

  float wc1row[3];
  wc1row[0] = wc1[m31*3+0]; wc1row[1] = wc1[m31*3+1]; wc1row[2] = wc1[m31*3+2];
  const float wcb1r = wcb1[m31];
  const double fs1r = (double)bn1g[m31]/sq, fb1r = (double)bn1b[m31];
  float wc2row[32];
  #pragma unroll
  for (int m=0;m<32;m++) wc2row[m] = wc2[lane*32 + m];
  const float wcb2r = wcb2[lane];
  const double fs2r = (double)bn2g[lane]/sq, fb2r = (double)bn2b[lane];
  float xcrow[6];
  #pragma unroll
  for (int c=0;c<6;c++) xcrow[c] = xc[lane*6 + c];
  const float xcbr = xcb[lane];
  const double fsxr = (double)xbng[lane]/sq, fbxr = (double)xbnb[lane];

  const int p = blockIdx.x*8 + wid;
  const int b = p >> 11, n = p & (NPTS-1);
  const float* xb = Xn + (size_t)b*NPTS*3;
  const float cen0 = xb[(size_t)n*3+0];
  const float cen1 = xb[(size_t)n*3+1];
  const float cen2 = xb[(size_t)n*3+2];
  const int* ip = idx + ((size_t)b*NPTS + n)*KNB;

  double w2r[KNB], hr[KNB];
  #pragma unroll
  for (int j=0;j<KNB;j++){
    const int id = ip[j];
    const float dif0 = __fadd_rn(xb[(size_t)id*3+0], -cen0);
    const float dif1 = __fadd_rn(xb[(size_t)id*3+1], -cen1);
    const float dif2 = __fadd_rn(xb[(size_t)id*3+2], -cen2);
    {
      float s = __fmul_rn(wc1row[0], dif0);
      s = __fadd_rn(s, __fmul_rn(wc1row[1], dif1));
      s = __fadd_rn(s, __fmul_rn(wc1row[2], dif2));
      s = __fadd_rn(s, wcb1r);
      const double w1v = lrelu_d((double)s * fs1r + fb1r, 0.01);
      if (lane < 32) w1bd[wid][lane] = w1v;
    }
    __builtin_amdgcn_wave_barrier();
    {
      double s2 = 0.0;
      #pragma unroll 8
      for (int m=0;m<32;m++) s2 += (double)wc2row[m] * w1bd[wid][m];
      s2 += (double)wcb2r;
      w2r[j] = lrelu_d(s2*fs2r + fb2r, 0.01);
    }
    {
      float s3 = __fmul_rn(xcrow[0], cen0);
      s3 = __fadd_rn(s3, __fmul_rn(xcrow[1], cen1));
      s3 = __fadd_rn(s3, __fmul_rn(xcrow[2], cen2));
      s3 = __fadd_rn(s3, __fmul_rn(xcrow[3], dif0));
      s3 = __fadd_rn(s3, __fmul_rn(xcrow[4], dif1));
      s3 = __fadd_rn(s3, __fmul_rn(xcrow[5], dif2));
      s3 = __fadd_rn(s3, xcbr);
      hr[j] = lrelu_d((double)s3*fsxr + fbxr, 0.01);
    }
    __builtin_amdgcn_wave_barrier();
  }

  double hw[KNB];
  {
    double mx = w2r[0];
    #pragma unroll
    for (int j=1;j<KNB;j++) mx = fmax(mx, w2r[j]);
    double ssum = 0.0;
    #pragma unroll
    for (int j=0;j<KNB;j++){ const double e = exp(w2r[j]-mx); w2r[j]=e; ssum+=e; }
    #pragma unroll
    for (int j=0;j<KNB;j++) hw[j] = hr[j]*(w2r[j]/ssum);
  }

  // phase 2: out[o] = sum_j sum_c hw[c][j]*oW[o][c][j]; oWT layout (j,c,o).
  // Direct coalesced global reads (oWT L2-hot); hwbd broadcast is per-wave.
  double acc = 0.0;
  #pragma unroll
  for (int j=0;j<KNB;j++){
    hwbd[wid][lane] = hw[j];
    __builtin_amdgcn_wave_barrier();
    const float* ow = oWT + (size_t)j*4096;
    double s = 0.0;
    #pragma unroll 8
    for (int c=0;c<64;c++) s += (double)ow[c*64 + lane]*hwbd[wid][c];
    acc += s;
    __builtin_amdgcn_wave_barrier();
  }
  outX[((size_t)b*64+lane)*NPTS + n] = acc + (double)ob[lane];
}

template<int CH>
__global__ void owt_kernel(const float* __restrict__ oW, float* __restrict__ oWT)
{
  const int i = blockIdx.x*256 + threadIdx.x;
  if (i < CH*CH*KNB){
    const int j  = i % KNB;
    const int c2 = (i / KNB) % CH;
    const int o  = i / (KNB*CH);
    oWT[((size_t)j*CH + c2)*CH + o] = oW[i];
  }
}

__global__ __launch_bounds__(256) void adain1_f64(
    double* __restrict__ X, const float* __restrict__ S)
{
  const int c = blockIdx.x, b = blockIdx.y;
  const int t = threadIdx.x;
  const size_t base = ((size_t)b*64 + c)*NPTS;
  __shared__ double red[256];
  double v[8];
  double s = 0.0;
  #pragma unroll
  for (int i=0;i<8;i++){
    double xv = X[base + t + i*256];
    xv = lrelu_d(xv, 0.2);
    v[i] = xv; s += xv;
  }
  red[t] = s; __syncthreads();
  for (int st=128; st>0; st>>=1){ if (t<st) red[t] += red[t+st]; __syncthreads(); }
  const double mean = red[0]/(double)NPTS;
  __syncthreads();
  double s2 = 0.0;
  #pragma unroll
  for (int i=0;i<8;i++){ const double d = v[i]-mean; s2 += d*d; }
  red[t] = s2; __syncthreads();
  for (int st=128; st>0; st>>=1){ if (t<st) red[t] += red[t+st]; __syncthreads(); }
  const double var  = red[0]/(double)NPTS;
  const double rstd = 1.0/sqrt(var + 1e-5);
  const float* g  = S + ((size_t)b*128 + c)*NPTS;
  const float* be = S + ((size_t)b*128 + 64 + c)*NPTS;
  #pragma unroll
  for (int i=0;i<8;i++){
    const int n = t + i*256;
    X[base+n] = (double)g[n]*((v[i]-mean)*rstd) + (double)be[n];
  }
}

// (B,64,N) f64 chan-major -> X1T64 (B,N,64) f64, X1f (B,N,64) f32, X1c (B,64,N) f32
__global__ __launch_bounds__(256) void transpose_cast64(
    const double* __restrict__ in, double* __restrict__ outT,
    float* __restrict__ outTf, float* __restrict__ outC)
{
  __shared__ double tile[64][65];
  const int b = blockIdx.y, n0 = blockIdx.x*64;
  const int t = threadIdx.x;
  for (int i=t; i<4096; i+=256){
    const int n=i&63, c=i>>6;
    const double v = in[((size_t)b*64+c)*NPTS + n0+n];
    tile[c][n] = v;
    outC[((size_t)b*64+c)*NPTS + n0+n] = (float)v;
  }
  __syncthreads();
  for (int i=t; i<4096; i+=256){
    const int c=i&63, n=i>>6;
    const double v = tile[c][n];
    outT [((size_t)b*NPTS+n0+n)*64 + c] = v;
    outTf[((size_t)b*NPTS+n0+n)*64 + c] = (float)v;
  }
}

// ---------------------------------------------------------------------------
// Kernel P: per-point center GEMMs (WCC, HCC).
// ---------------------------------------------------------------------------
__global__ __launch_bounds__(256) void kernelP(
    const float* __restrict__ x1c, const float* __restrict__ wc1,
    const float* __restrict__ xc,
    float* __restrict__ WCC, float* __restrict__ HCC)
{
  __shared__ float As[16][68];
  __shared__ float Bs[16][132];
  const int b = blockIdx.z;
  const int y = blockIdx.y;
  const int n0 = blockIdx.x*128;
  const int t = threadIdx.x;
  const int tm = t>>4, tn = t&15;
  float acc[4][8] = {};
  for (int k0=0; k0<64; k0+=16){
    #pragma unroll
    for (int s=0;s<4;s++){
      const int i = t + s*256;
      const int k = i&15, m = i>>4;
      float w;
      if (y == 0) w = wc1[(size_t)m*64 + k0 + k];
      else {
        const int c = (y-1)*64 + m;
        w = xc[(size_t)c*128 + k0 + k] - xc[(size_t)c*128 + 64 + k0 + k];
      }
      As[k][m] = w;
    }
    #pragma unroll
    for (int s=0;s<8;s++){
      const int i = t + s*256;
      const int n = i&127, kk = i>>7;
      Bs[kk][n] = x1c[((size_t)b*64 + k0 + kk)*NPTS + n0 + n];
    }
    __syncthreads();
    #pragma unroll
    for (int k=0;k<16;k++){
      float4 a4 = *(const float4*)&As[k][tm*4];
      const float av[4] = {a4.x, a4.y, a4.z, a4.w};
      #pragma unroll
      for (int j=0;j<8;j++){
        const float bv = Bs[k][tn + j*16];
        #pragma unroll
        for (int i2=0;i2<4;i2++) acc[i2][j] += av[i2]*bv;
      }
    }
    __syncthreads();
  }
  #pragma unroll
  for (int i2=0;i2<4;i2++){
    const int m = tm*4 + i2;
    #pragma unroll
    for (int j=0;j<8;j++){
      const int n = n0 + tn + j*16;
      if (y == 0) WCC[((size_t)b*64 + m)*NPTS + n] = acc[i2][j];
      else        HCC[((size_t)b*128 + (y-1)*64 + m)*NPTS + n] = acc[i2][j];
    }
  }
}

// ---------------------------------------------------------------------------
// Kernel A: w1 = lrelu(bn1( wc1@nbr - WCC + wcb1 ))
// ---------------------------------------------------------------------------
__global__ __launch_bounds__(256) void kernelA(
    const float* __restrict__ X1f, const int* __restrict__ IDX,
    const float* __restrict__ WCC,
    const float* __restrict__ wc1, const float* __restrict__ wcb1,
    const float* __restrict__ bn1g, const float* __restrict__ bn1b,
    float* __restrict__ W1, int bbase)
{
  __shared__ float wc1T[64*68];
  __shared__ float nbr[64*132];
  __shared__ int idx_l[128];
  const int b = bbase + blockIdx.z;
  const int n0 = blockIdx.x*128;
  const int t = threadIdx.x;
  const float* xb = X1f + (size_t)b*NPTS*64;

  if (t < 128){
    const int n = n0 + t;
    idx_l[t] = IDX[((size_t)b*NPTS + n/10)*KNB + (n%10)];
  }
  for (int i=t; i<4096; i+=256){
    const int k = i&63, m = i>>6;
    wc1T[k*68 + m] = wc1[(size_t)m*64 + k];
  }
  __syncthreads();
  const float4* xb4 = (const float4*)xb;
  #pragma unroll
  for (int r=0; r<8; r++){
    const int i = t + r*256;
    const int pos = i>>4, q4 = i&15;
    const float4 v = xb4[(size_t)idx_l[pos]*16 + q4];
    nbr[(q4*4+0)*132 + pos] = v.x;
    nbr[(q4*4+1)*132 + pos] = v.y;
    nbr[(q4*4+2)*132 + pos] = v.z;
    nbr[(q4*4+3)*132 + pos] = v.w;
  }
  __syncthreads();

  const int tm = t>>4, tn = t&15;
  float acc[4][8] = {};
  #pragma unroll 4
  for (int k=0;k<64;k++){
    float4 a4 = *(const float4*)&wc1T[k*68 + tm*4];
    const float av[4] = {a4.x, a4.y, a4.z, a4.w};
    #pragma unroll
    for (int j=0;j<8;j++){
      const float bv = nbr[k*132 + tn + j*16];
      #pragma unroll
      for (int i2=0;i2<4;i2++) acc[i2][j] += av[i2]*bv;
    }
  }
  const float rs = 1.f/sqrtf(1.f + 1e-5f);
  #pragma unroll
  for (int i2=0;i2<4;i2++){
    const int m = tm*4 + i2;
    const float bias = wcb1[m];
    const float sc = bn1g[m]*rs, bb = bn1b[m];
    #pragma unroll
    for (int j=0;j<8;j++){
      const int n = n0 + tn + j*16;
      const int p = n/10;
      float v = acc[i2][j] - WCC[((size_t)b*64 + m)*NPTS + p] + bias;
      v = lrelu(v*sc + bb, 0.01f);
      W1[((size_t)(b-bbase)*64 + m)*NT + n] = v;
    }
  }
}

// ---------------------------------------------------------------------------
// Kernel C (chunked channels: 2 x 64): fused w2-GEMM + h-GEMM + softmax +
// partial output einsum. LDS union 19200 floats (76.8 KB) -> 2 blocks/CU.
// ---------------------------------------------------------------------------
#define C_WC2T 0
#define C_XCDT 4352
#define C_W1S  8704
#define C_NBRS 13952
#define C_TOT  19200
#define C_HW   0       /* [8][648] = 5184 */
#define C_OWL  5184    /* [128][65] = 8320 -> end 13504 */

__global__ __launch_bounds__(256) void kernelC(
    const float* __restrict__ X1f, const int* __restrict__ IDX,
    const float* __restrict__ W1, const float* __restrict__ HCC,
    const float* __restrict__ wc2, const float* __restrict__ wcb2,
    const float* __restrict__ bn2g, const float* __restrict__ bn2b,
    const float* __restrict__ xc,  const float* __restrict__ xcb,
    const float* __restrict__ xbng, const float* __restrict__ xbnb,
    const float* __restrict__ oW, const float* __restrict__ ob,
    float* __restrict__ X2, int bbase)
{
  __shared__ float smC[C_TOT];
  __shared__ int idxC[80];
  const int b = bbase + blockIdx.z;
  const int n0 = blockIdx.x*80;
  const int p0 = n0/10;
  const int t = threadIdx.x;
  const float* xb = X1f + (size_t)b*NPTS*64;

  if (t < 80){
    const int n = n0 + t;
    idxC[t] = IDX[((size_t)b*NPTS + n/10)*KNB + (n%10)];
  }
  __syncthreads();

  const int tmv = t>>4, tnv = t&15, tnv5 = tnv*5;
  const int p_loc = tnv>>1, jh5 = (tnv&1)*5;
  const int o = t&127, phalf = t>>7;
  const float rs = 1.f/sqrtf(1.f + 1e-5f);
  float acc2[4] = {};

  for (int ch=0; ch<2; ch++){
    for (int i=t; i<4096; i+=256){
      const int k = i&63, cl = i>>6;
      smC[C_WC2T + k*68 + cl] = wc2[(size_t)(ch*64+cl)*64 + k];
      smC[C_XCDT + k*68 + cl] = xc[(size_t)(ch*64+cl)*128 + 64 + k];
    }
    for (int i=t; i<5120; i+=256){
      const int n = i%80, k = i/80;
      smC[C_W1S + k*82 + n] = W1[((size_t)(b-bbase)*64 + k)*NT + n0 + n];
    }
    {
      const float4* xb4 = (const float4*)xb;
      #pragma unroll
      for (int r=0;r<5;r++){
        const int i = t + r*256;
        const int pos = i>>4, q4 = i&15;
        const float4 v = xb4[(size_t)idxC[pos]*16 + q4];
        smC[C_NBRS + (q4*4+0)*82 + pos] = v.x;
        smC[C_NBRS + (q4*4+1)*82 + pos] = v.y;
        smC[C_NBRS + (q4*4+2)*82 + pos] = v.z;
        smC[C_NBRS + (q4*4+3)*82 + pos] = v.w;
      }
    }
    __syncthreads();

    float accw[4][5] = {}, acch[4][5] = {};
    #pragma unroll 2
    for (int k=0;k<64;k++){
      float4 a4 = *(const float4*)&smC[C_WC2T + k*68 + tmv*4];
      float4 x4 = *(const float4*)&smC[C_XCDT + k*68 + tmv*4];
      const float av[4] = {a4.x,a4.y,a4.z,a4.w};
      const float xv[4] = {x4.x,x4.y,x4.z,x4.w};
      float bw[5], bh[5];
      #pragma unroll
      for (int j=0;j<5;j++){
        bw[j] = smC[C_W1S  + k*82 + tnv5 + j];
        bh[j] = smC[C_NBRS + k*82 + tnv5 + j];
      }
      #pragma unroll
      for (int i2=0;i2<4;i2++)
        #pragma unroll
        for (int j=0;j<5;j++){ accw[i2][j]+=av[i2]*bw[j]; acch[i2][j]+=xv[i2]*bh[j]; }
    }

    float hwreg[4][5];
    #pragma unroll
    for (int i2=0;i2<4;i2++){
      const int c = ch*64 + tmv*4 + i2;
      const float s2 = bn2g[c]*rs, b2 = bn2b[c], cb2 = wcb2[c];
      const float sx = xbng[c]*rs, bx = xbnb[c], cbx = xcb[c];
      const float hcc = HCC[((size_t)b*128 + c)*NPTS + p0 + p_loc];
      float w2[5], hv[5];
      #pragma unroll
      for (int j=0;j<5;j++){
        w2[j] = lrelu((accw[i2][j] + cb2)*s2 + b2, 0.01f);
        hv[j] = lrelu((acch[i2][j] + hcc + cbx)*sx + bx, 0.01f);
      }
      float mx = w2[0];
      #pragma unroll
      for (int j=1;j<5;j++) mx = fmaxf(mx, w2[j]);
      mx = fmaxf(mx, __shfl_xor(mx, 1));
      float ssum = 0.f;
      #pragma unroll
      for (int j=0;j<5;j++){ w2[j] = expf(w2[j]-mx); ssum += w2[j]; }
      ssum += __shfl_xor(ssum, 1);
      const float inv = 1.f/ssum;
      #pragma unroll
      for (int j=0;j<5;j++) hwreg[i2][j] = hv[j]*(w2[j]*inv);
    }
    __syncthreads();

    #pragma unroll
    for (int i2=0;i2<4;i2++){
      const int cl = tmv*4 + i2;
      #pragma unroll
      for (int j=0;j<5;j++)
        smC[C_HW + p_loc*648 + cl*10 + jh5 + j] = hwreg[i2][j];
    }
    __syncthreads();

    for (int kc=0; kc<640; kc+=64){
      #pragma unroll
      for (int r=0;r<32;r++){
        const int i = t + r*256;
        const int oo = i>>6, kk = i&63;
        smC[C_OWL + oo*65 + kk] = oW[(size_t)oo*1280 + ch*640 + kc + kk];
      }
      __syncthreads();
      #pragma unroll 4
      for (int kk=0; kk<64; kk+=4){
        const float w0 = smC[C_OWL + o*65 + kk];
        const float w1v= smC[C_OWL + o*65 + kk+1];
        const float w2v= smC[C_OWL + o*65 + kk+2];
        const float w3v= smC[C_OWL + o*65 + kk+3];
        #pragma unroll
        for (int pp=0;pp<4;pp++){
          const float4 h4 = *(const float4*)&smC[C_HW + (phalf*4+pp)*648 + kc + kk];
          acc2[pp] += w0*h4.x + w1v*h4.y + w2v*h4.z + w3v*h4.w;
        }
      }
      __syncthreads();
    }
  }
  const float obv = ob[o];
  #pragma unroll
  for (int pp=0;pp<4;pp++)
    X2[((size_t)b*128 + o)*NPTS + p0 + phalf*4 + pp] = acc2[pp] + obv;
}

// ---------------------------------------------------------------------------
template<int CH>
__global__ __launch_bounds__(256) void adain_kernel(
    float* __restrict__ X, const float* __restrict__ S)
{
  const int c = blockIdx.x, b = blockIdx.y;
  const int t = threadIdx.x;
  const size_t base = ((size_t)b*CH + c)*NPTS;
  __shared__ float red[256];
  float v[8];
  float s = 0.f;
  #pragma unroll
  for (int i=0;i<8;i++){
    float xv = X[base + t + i*256];
    xv = lrelu(xv, 0.2f);
    v[i] = xv; s += xv;
  }
  red[t] = s; __syncthreads();
  for (int st=128; st>0; st>>=1){ if (t<st) red[t] += red[t+st]; __syncthreads(); }
  const float mean = red[0]*(1.f/NPTS);
  __syncthreads();
  float s2 = 0.f;
  #pragma unroll
  for (int i=0;i<8;i++){ const float d = v[i]-mean; s2 += d*d; }
  red[t] = s2; __syncthreads();
  for (int st=128; st>0; st>>=1){ if (t<st) red[t] += red[t+st]; __syncthreads(); }
  const float var  = red[0]*(1.f/NPTS);
  const float rstd = 1.f/sqrtf(var + 1e-5f);
  const float* g  = S + ((size_t)b*2*CH + c)*NPTS;
  const float* be = S + ((size_t)b*2*CH + CH + c)*NPTS;
  #pragma unroll
  for (int i=0;i<8;i++){
    const int n = t + i*256;
    X[base+n] = g[n]*((v[i]-mean)*rstd) + be[n];
  }
}

__global__ __launch_bounds__(256) void maxn_kernel(const float* __restrict__ X, float* __restrict__ FG)
{
  const int c = blockIdx.x, b = blockIdx.y;
  const int t = threadIdx.x;
  const float* p = X + ((size_t)b*128 + c)*NPTS;
  __shared__ float red[256];
  float m = -3.4e38f;
  for (int i=t; i<NPTS; i+=256) m = fmaxf(m, p[i]);
  red[t] = m; __syncthreads();
  for (int st=128; st>0; st>>=1){ if (t<st) red[t] = fmaxf(red[t], red[t+st]); __syncthreads(); }
  if (t == 0) FG[b*128+c] = red[0];
}

__global__ __launch_bounds__(512) void fc_kernel(
    const float* __restrict__ FG,
    const float* __restrict__ gW1, const float* __restrict__ gb1,
    const float* __restrict__ gbn1g, const float* __restrict__ gbn1b,
    const float* __restrict__ gW2, const float* __restrict__ gb2,
    const float* __restrict__ gbn2g, const float* __restrict__ gbn2b,
    const float* __restrict__ tW1, const float* __restrict__ tb1,
    float* __restrict__ FGP)
{
  const int b = blockIdx.x, t = threadIdx.x;
  __shared__ float fg[128], h1[128], h2[512];
  const float rs = 1.f/sqrtf(1.f + 1e-5f);
  if (t < 128) fg[t] = FG[b*128+t];
  __syncthreads();
  if (t < 128){
    float s = 0.f;
    for (int c=0;c<128;c++) s += gW1[t*128+c]*fg[c];
    s += gb1[t];
    s = s*(gbn1g[t]*rs) + gbn1b[t];
    h1[t] = lrelu(s, 0.01f);
  }
  __syncthreads();
  {
    float s = 0.f;
    for (int c=0;c<128;c++) s += gW2[t*128+c]*h1[c];
    s += gb2[t];
    s = s*(gbn2g[t]*rs) + gbn2b[t];
    h2[t] = lrelu(s, 0.01f);
  }
  __syncthreads();
  if (t < 256){
    float s = tb1[t];
    for (int c=0;c<512;c++) s += tW1[(size_t)t*640 + c]*h2[c];
    FGP[b*256+t] = s;
  }
}

__global__ __launch_bounds__(256) void t3_kernel(
    const float* __restrict__ T2, const float* __restrict__ tW3,
    const float* __restrict__ tb3, float* __restrict__ outp)
{
  __shared__ float w[192];
  const int t = threadIdx.x;
  if (t < 192) w[t] = tW3[t];
  __syncthreads();
  const int b = blockIdx.y;
  const int n = blockIdx.x*256 + t;
  float a0 = tb3[0], a1 = tb3[1], a2 = tb3[2];
  for (int c=0;c<64;c++){
    const float v = T2[((size_t)b*64+c)*NPTS + n];
    a0 += w[c]*v; a1 += w[64+c]*v; a2 += w[128+c]*v;
  }
  float* op = outp + ((size_t)b*NPTS + n)*3;
  op[0]=a0; op[1]=a1; op[2]=a2;
}

// ---------------------------------------------------------------------------
extern "C" void kernel_launch(void* const* d_in, const int* in_sizes, int n_in,
                              void* d_out, int out_size, void* d_ws, size_t ws_size,
                              hipStream_t stream)
{
  (void)in_sizes; (void)n_in; (void)out_size; (void)ws_size;
  const float* z    = (const float*)d_in[0];
  const float* x    = (const float*)d_in[1];
  const float* hW1  = (const float*)d_in[2];
  const float* hb1  = (const float*)d_in[3];
  const float* hW2  = (const float*)d_in[4];
  const float* hb2  = (const float*)d_in[5];
  const float* e1_wc1 = (const float*)d_in[6];
  const float* e1_wcb1= (const float*)d_in[7];
  const float* e1_bn1g= (const float*)d_in[8];
  const float* e1_bn1b= (const float*)d_in[9];
  const float* e1_wc2 = (const float*)d_in[10];
  const float* e1_wcb2= (const float*)d_in[11];
  const float* e1_bn2g= (const float*)d_in[12];
  const float* e1_bn2b= (const float*)d_in[13];
  const float* e1_xc  = (const float*)d_in[14];
  const float* e1_xcb = (const float*)d_in[15];
  const float* e1_xbng= (const float*)d_in[16];
  const float* e1_xbnb= (const float*)d_in[17];
  const float* e1_oW  = (const float*)d_in[18];
  const float* e1_ob  = (const float*)d_in[19];
  const float* a1_W   = (const float*)d_in[20];
  const float* a1_b   = (const float*)d_in[21];
  const float* e2_wc1 = (const float*)d_in[22];
  const float* e2_wcb1= (const float*)d_in[23];
  const float* e2_bn1g= (const float*)d_in[24];
  const float* e2_bn1b= (const float*)d_in[25];
  const float* e2_wc2 = (const float*)d_in[26];
  const float* e2_wcb2= (const float*)d_in[27];
  const float* e2_bn2g= (const float*)d_in[28];
  const float* e2_bn2b= (const float*)d_in[29];
  const float* e2_xc  = (const float*)d_in[30];
  const float* e2_xcb = (const float*)d_in[31];
  const float* e2_xbng= (const float*)d_in[32];
  const float* e2_xbnb= (const float*)d_in[33];
  const float* e2_oW  = (const float*)d_in[34];
  const float* e2_ob  = (const float*)d_in[35];
  const float* a2_W   = (const float*)d_in[36];
  const float* a2_b   = (const float*)d_in[37];
  const float* gW1    = (const float*)d_in[38];
  const float* gb1    = (const float*)d_in[39];
  const float* gbn1g  = (const float*)d_in[40];
  const float* gbn1b  = (const float*)d_in[41];
  const float* gW2    = (const float*)d_in[42];
  const float* gb2    = (const float*)d_in[43];
  const float* gbn2g  = (const float*)d_in[44];
  const float* gbn2b  = (const float*)d_in[45];
  const float* tW1    = (const float*)d_in[46];
  const float* tb1    = (const float*)d_in[47];
  const float* tW2    = (const float*)d_in[48];
  const float* tb2    = (const float*)d_in[49];
  const float* tW3    = (const float*)d_in[50];
  const float* tb3    = (const float*)d_in[51];
  float* out = (float*)d_out;
  float* ws  = (float*)d_ws;

  // workspace layout (float units) — total ~18.6M floats ≈ 74.4 MB
  size_t off = 0;
  float*  ST    = ws + off; off += (size_t)BATCH*128*NPTS;    // 2,097,152
  float*  Sbuf  = ws + off; off += (size_t)BATCH*256*NPTS;    // 4,194,304
  float*  X1f   = ws + off; off += (size_t)BATCH*NPTS*64;     // 1,048,576
  float*  X2    = ws + off; off += (size_t)BATCH*128*NPTS;    // 2,097,152
  float*  T1    = ws + off; off += (size_t)BATCH*256*NPTS;    // 4,194,304
  float*  T2    = ws + off; off += (size_t)BATCH*64*NPTS;     //   524,288
  int*    IDX   = (int*)(ws + off); off += (size_t)BATCH*NPTS*KNB;  // 163,840
  float*  OW1T  = ws + off; off += (size_t)64*64*KNB;         //  40,960
  float*  XN3f  = ws + off; off += (size_t)BATCH*NPTS;        //  16,384
  double* XN64  = (double*)(ws + off); off += (size_t)2*BATCH*NPTS; // 32,768
  float*  FG    = ws + off; off += (size_t)BATCH*128;
  float*  FGP   = ws + off; off += (size_t)BATCH*256;
  off = (off + 1) & ~(size_t)1;
  double* X1_64 = (double*)(ws + off); off += (size_t)2*BATCH*64*NPTS;  // 2,097,152 fl
  double* X1T64 = (double*)(ws + off); off += (size_t)2*BATCH*NPTS*64;  // 2,097,152 fl

  // aliases (time-disjoint; liveness table):
  //  - TOPD/TOPI: live only between knn_part3 and knn_merge
  //  - TOPF: (float*)X1_64, exact fit; X1_64 dead after transpose_cast64
  //  - TOPI2: (int*)T1; T1 dead between style head and kernelA
  //  - X1c = Sbuf[0:1M]: written by transpose_cast64, read by kernelP
  double* TOPD  = (double*)T1;
  int*    TOPI  = (int*)Sbuf;
  float*  TOPF  = (float*)X1_64;
  int*    TOPI2 = (int*)T1;
  float*  X1c   = Sbuf;
  float*  WCC   = Sbuf + 1048576;
  float*  HCC   = Sbuf + 2097152;
  float*  W1    = T1;

  // oW transpose for edge1
  owt_kernel<64><<<(64*64*KNB+255)/256, 256, 0, stream>>>(e1_oW, OW1T);

  // style head (np-exact f32)
  head1_exact<<<dim3(32,2,8), 256, 0, stream>>>(x, z, hW1, hb1, T1);
  gemm_bn<128,128,true><<<dim3(NPTS/128,1,8), 256, 0, stream>>>(
      T1, NPTS, (size_t)128*NPTS, 0, hW2, 128, 0, hb2, nullptr, nullptr, nullptr, 0,
      ST, NPTS, (size_t)128*NPTS, 128, 1, 0.01f, 0);

  // edge block 1
  norms3_f32<<<64, 256, 0, stream>>>(x, XN3f);
  knn_part3<<<512, 256, 0, stream>>>(x, XN3f, TOPD, TOPI);
  knn_merge_kernel<<<64, 256, 0, stream>>>(TOPD, TOPI, IDX);
  edge1_f64<<<2048, 512, 0, stream>>>(
      x, IDX, e1_wc1, e1_wcb1, e1_bn1g, e1_bn1b, e1_wc2, e1_wcb2, e1_bn2g, e1_bn2b,
      e1_xc, e1_xcb, e1_xbng, e1_xbnb, OW1T, e1_ob, X1_64);
  gemm_bn<128,128,true><<<dim3(NPTS/128,1,8), 256, 0, stream>>>(
      ST, NPTS, (size_t)128*NPTS, 0, a1_W, 128, 0, a1_b, nullptr, nullptr, nullptr, 0,
      Sbuf, NPTS, (size_t)128*NPTS, 128, 0, 0.f, 0);
  adain1_f64<<<dim3(64,8), 256, 0, stream>>>(X1_64, Sbuf);

  // x1 -> n-major f64 + f32, chan-major f32
  transpose_cast64<<<dim3(32,8), 256, 0, stream>>>(X1_64, X1T64, X1f, X1c);

  // block2 kNN: f32 coarse (LDS-tiled) + f64 refine
  norms64_f32<<<64, 256, 0, stream>>>(X1f, XN3f);
  norms64d<<<64, 256, 0, stream>>>(X1T64, XN64);
  knn_coarse<<<512, 256, 0, stream>>>(X1f, XN3f, TOPF, TOPI2);
  knn_refine<<<64, 256, 0, stream>>>(TOPF, TOPI2, X1T64, XN64, IDX);

  // edge block 2 pipeline
  kernelP<<<dim3(16,3,8), 256, 0, stream>>>(X1c, e2_wc1, e2_xc, WCC, HCC);
  for (int lb=0; lb<4; lb++){
    const int bbase = lb*2;
    kernelA<<<dim3(NT/128,1,2), 256, 0, stream>>>(
        X1f, IDX, WCC, e2_wc1, e2_wcb1, e2_bn1g, e2_bn1b, W1, bbase);
    kernelC<<<dim3(NT/80,1,2), 256, 0, stream>>>(
        X1f, IDX, W1, HCC, e2_wc2, e2_wcb2, e2_bn2g, e2_bn2b,
        e2_xc, e2_xcb, e2_xbng, e2_xbnb, e2_oW, e2_ob, X2, bbase);
  }

  // adain2
  gemm_bn<128,128><<<dim3(NPTS/128,2,8), 256, 0, stream>>>(
      ST, NPTS, (size_t)128*NPTS, 0, a2_W, 128, 0, a2_b, nullptr, nullptr, nullptr, 0,
      Sbuf, NPTS, (size_t)256*NPTS, 128, 0, 0.f, 0);
  adain_kernel<128><<<dim3(128,8), 256, 0, stream>>>(X2, Sbuf);

  // global feature + final MLP
  maxn_kernel<<<dim3(128,8), 256, 0, stream>>>(X2, FG);
  fc_kernel<<<8, 512, 0, stream>>>(FG, gW1, gb1, gbn1g, gbn1b, gW2, gb2, gbn2g, gbn2b, tW1, tb1, FGP);
  gemm_bn<128,128><<<dim3(NPTS/128,2,8), 256, 0, stream>>>(
      X2, NPTS, (size_t)128*NPTS, 0, tW1, 640, 512, nullptr, nullptr, nullptr, FGP, 256,
      T1, NPTS, (size_t)256*NPTS, 128, 1, 0.01f, 0);
  gemm_bn<64,128><<<dim3(NPTS/128,1,8), 256, 0, stream>>>(
      T1, NPTS, (size_t)256*NPTS, 0, tW2, 256, 0, tb2, nullptr, nullptr, nullptr, 0,
      T2, NPTS, (size_t)64*NPTS, 256, 1, 0.01f, 0);
  t3_kernel<<<dim3(8,8), 256, 0, stream>>>(T2, tW3, tb3, out);
}